// Round 6
// baseline (482.040 us; speedup 1.0000x reference)
//
#include <hip/hip_runtime.h>
#include <hip/hip_bf16.h>

#define BB 2
#define LL 2048
#define DM 256
#define DI 512
#define NST 16
#define RDT 16
#define KC 4
#define NLAY 4
#define DOUT 10
#define XDIM 48            // R + 2N
#define TOK (BB*LL)        // 4096
#define EPSF 1e-5f
#define CHUNK 16
#define NCH (LL/CHUNK)     // 128

typedef __bf16 bf16x8 __attribute__((ext_vector_type(8)));
typedef __bf16 bf16x4 __attribute__((ext_vector_type(4)));
typedef float  f32x4  __attribute__((ext_vector_type(4)));

__device__ __forceinline__ float sigmoid_f(float x) { return 1.0f / (1.0f + __expf(-x)); }

// ---------------- weight cast fp32 -> bf16 (once per call) ----------------
__global__ void cast_w_kernel(const float* __restrict__ a, const float* __restrict__ b,
                              const float* __restrict__ c,
                              __bf16* __restrict__ ab, __bf16* __restrict__ bb,
                              __bf16* __restrict__ cbf,
                              int na, int nb, int nc) {
  int stride = gridDim.x * 256;
  for (int i = blockIdx.x*256 + threadIdx.x; i < na; i += stride) ab[i] = (__bf16)a[i];
  for (int i = blockIdx.x*256 + threadIdx.x; i < nb; i += stride) bb[i] = (__bf16)b[i];
  for (int i = blockIdx.x*256 + threadIdx.x; i < nc; i += stride) cbf[i] = (__bf16)c[i];
}

// ------- residual add + layernorm; first layer reads embedding directly -------
__global__ void add_ln_kernel(float* __restrict__ residual, const float* __restrict__ hidden,
                              const int* __restrict__ ids, const float* __restrict__ emb,
                              const float* __restrict__ w, const float* __restrict__ bia,
                              float* __restrict__ out, __bf16* __restrict__ out_bf,
                              int first, int write32) {
  int t = blockIdx.x, d = threadIdx.x;
  __shared__ float ws8[8];
  float r;
  if (first) r = emb[ids[t]*DM + d];
  else       r = hidden[t*DM + d] + residual[t*DM + d];
  residual[t*DM + d] = r;
  float s = r;
  #pragma unroll
  for (int o = 32; o; o >>= 1) s += __shfl_down(s, o);
  if ((d & 63) == 0) ws8[d >> 6] = s;
  __syncthreads();
  float mean = (ws8[0] + ws8[1] + ws8[2] + ws8[3]) * (1.0f/DM);
  float diff = r - mean;
  float q = diff * diff;
  #pragma unroll
  for (int o = 32; o; o >>= 1) q += __shfl_down(q, o);
  if ((d & 63) == 0) ws8[4 + (d >> 6)] = q;
  __syncthreads();
  float var = (ws8[4] + ws8[5] + ws8[6] + ws8[7]) * (1.0f/DM);
  float v = diff * rsqrtf(var + EPSF) * w[d] + bia[d];
  if (write32) out[t*DM + d] = v;
  out_bf[t*DM + d] = (__bf16)v;
}

// ------- in_proj GEMM, direct-fragment style (xproj16 pattern, verified) -------
// grid (2, TOK/16) x 512 thr. Wave = 16 rows x 64 cols, full K=256, no LDS, no
// barriers. A rows shared by all 8 waves of a block -> L1 hits; W is L2-resident.
__global__ __launch_bounds__(512, 4) void gemm_in_d(const __bf16* __restrict__ A,
                                                    const __bf16* __restrict__ W,
                                                    __bf16* __restrict__ xm,
                                                    __bf16* __restrict__ zg) {
  int tid = threadIdx.x;
  int lane = tid & 63, wv = tid >> 6;         // 8 waves
  int bm = blockIdx.y * 16;
  int row = bm + (lane & 15);
  int kg = (lane >> 4) * 8;
  int be = blockIdx.x * 512 + wv * 64;        // this wave's 64-col slice
  f32x4 acc[4];
  #pragma unroll
  for (int e = 0; e < 4; ++e) acc[e] = (f32x4){0.f, 0.f, 0.f, 0.f};
  for (int k0 = 0; k0 < DM; k0 += 32) {
    bf16x8 av = *(const bf16x8*)&A[(size_t)row*DM + k0 + kg];
    #pragma unroll
    for (int e = 0; e < 4; ++e) {
      bf16x8 bv = *(const bf16x8*)&W[(size_t)(be + e*16 + (lane & 15))*DM + k0 + kg];
      acc[e] = __builtin_amdgcn_mfma_f32_16x16x32_bf16(av, bv, acc[e], 0, 0, 0);
    }
  }
  int r0 = bm + (lane >> 4)*4;
  int cb = lane & 15;
  if (blockIdx.x == 0) {          // cols 0..511 -> xm
    #pragma unroll
    for (int e = 0; e < 4; ++e)
      #pragma unroll
      for (int r = 0; r < 4; ++r)
        xm[(size_t)(r0 + r)*DI + be + e*16 + cb] = (__bf16)acc[e][r];
  } else {                        // cols 512..1023 -> zg = silu(z)
    int ze = be - DI;
    #pragma unroll
    for (int e = 0; e < 4; ++e)
      #pragma unroll
      for (int r = 0; r < 4; ++r) {
        float zv = acc[e][r];
        zg[(size_t)(r0 + r)*DI + ze + e*16 + cb] = (__bf16)(zv * sigmoid_f(zv));
      }
  }
}

// ------- out_proj GEMM, direct-fragment style -------
// grid (2, TOK/16) x 256 thr. Wave = 16 rows x 32 cols, full K=512.
__global__ __launch_bounds__(256, 4) void gemm_out_d(const __bf16* __restrict__ A,
                                                     const __bf16* __restrict__ W,
                                                     float* __restrict__ C) {
  int tid = threadIdx.x;
  int lane = tid & 63, wv = tid >> 6;         // 4 waves
  int bm = blockIdx.y * 16;
  int row = bm + (lane & 15);
  int kg = (lane >> 4) * 8;
  int be = blockIdx.x * 128 + wv * 32;        // this wave's 32-col slice
  f32x4 acc[2];
  #pragma unroll
  for (int e = 0; e < 2; ++e) acc[e] = (f32x4){0.f, 0.f, 0.f, 0.f};
  for (int k0 = 0; k0 < DI; k0 += 32) {
    bf16x8 av = *(const bf16x8*)&A[(size_t)row*DI + k0 + kg];
    #pragma unroll
    for (int e = 0; e < 2; ++e) {
      bf16x8 bv = *(const bf16x8*)&W[(size_t)(be + e*16 + (lane & 15))*DI + k0 + kg];
      acc[e] = __builtin_amdgcn_mfma_f32_16x16x32_bf16(av, bv, acc[e], 0, 0, 0);
    }
  }
  int r0 = bm + (lane >> 4)*4;
  int cb = lane & 15;
  #pragma unroll
  for (int e = 0; e < 2; ++e)
    #pragma unroll
    for (int r = 0; r < 4; ++r)
      C[(size_t)(r0 + r)*DM + be + e*16 + cb] = acc[e][r];
}

// ------- x_proj, M-tile 16, 8 waves split K (64 each), no main-loop barriers -------
__global__ __launch_bounds__(512, 2) void xproj16(const __bf16* __restrict__ xm,
                                                  const float* __restrict__ cw,
                                                  const float* __restrict__ cb,
                                                  const __bf16* __restrict__ Wbf,
                                                  float* __restrict__ out,
                                                  __bf16* __restrict__ xc) {
  __shared__ float red[8][3][16][16];   // 24 KB
  int tid = threadIdx.x;
  int lane = tid & 63, w = tid >> 6;    // 8 waves
  int bm = blockIdx.x * 16;
  int row = bm + (lane & 15);
  int l = row & (LL - 1);
  int kg = (lane >> 4) * 8;
  f32x4 acc[3];
  #pragma unroll
  for (int e = 0; e < 3; ++e) acc[e] = (f32x4){0.f, 0.f, 0.f, 0.f};
  #pragma unroll
  for (int ks = 0; ks < 2; ++ks) {
    int ch = w*64 + ks*32 + kg;
    bf16x8 v0 = *(const bf16x8*)&xm[(size_t)row*DI + ch];
    bf16x8 v1 = (l >= 1) ? *(const bf16x8*)&xm[(size_t)(row-1)*DI + ch] : (bf16x8)(__bf16)0;
    bf16x8 v2 = (l >= 2) ? *(const bf16x8*)&xm[(size_t)(row-2)*DI + ch] : (bf16x8)(__bf16)0;
    bf16x8 v3 = (l >= 3) ? *(const bf16x8*)&xm[(size_t)(row-3)*DI + ch] : (bf16x8)(__bf16)0;
    bf16x8 a8;
    #pragma unroll
    for (int j = 0; j < 8; ++j) {
      float4 cwv = *(const float4*)&cw[(ch + j)*KC];
      float cv = cb[ch + j];
      cv = fmaf(cwv.x, (float)v3[j], cv);
      cv = fmaf(cwv.y, (float)v2[j], cv);
      cv = fmaf(cwv.z, (float)v1[j], cv);
      cv = fmaf(cwv.w, (float)v0[j], cv);
      a8[j] = (__bf16)(cv * sigmoid_f(cv));
    }
    *(bf16x8*)&xc[(size_t)row*DI + ch] = a8;     // side-output for the scan
    #pragma unroll
    for (int e = 0; e < 3; ++e) {
      bf16x8 bv = *(const bf16x8*)&Wbf[(size_t)(e*16 + (lane & 15))*DI + ch];
      acc[e] = __builtin_amdgcn_mfma_f32_16x16x32_bf16(a8, bv, acc[e], 0, 0, 0);
    }
  }
  #pragma unroll
  for (int e = 0; e < 3; ++e)
    #pragma unroll
    for (int r = 0; r < 4; ++r)
      red[w][e][(lane >> 4)*4 + r][lane & 15] = acc[e][r];
  __syncthreads();
  for (int idx = tid; idx < 768; idx += 512) {
    int e = idx >> 8, rr = (idx >> 4) & 15, cc = idx & 15;
    float s = 0.f;
    #pragma unroll
    for (int w8 = 0; w8 < 8; ++w8) s += red[w8][e][rr][cc];
    out[(size_t)(bm + rr)*XDIM + e*16 + cc] = s;
  }
}

// ---------------- chunked selective scan (CHUNK=16, 512 blocks) ----------------
// pass1 reads precomputed xc; emits ylocal = C.h_loc + Dp*xc and cs = cumsum(delta).
__global__ __launch_bounds__(256) void scan_pass1(
    const __bf16* __restrict__ xc, const float* __restrict__ xdbl,
    const float* __restrict__ dtw, const float* __restrict__ dtb,
    const float* __restrict__ A_log, const float* __restrict__ Dp,
    float* __restrict__ hloc, float* __restrict__ dsum,
    float* __restrict__ ylocal, float* __restrict__ csout) {
  __shared__ __align__(16) float DBC[CHUNK][48];  // [l][0:16 dt | 16:32 B | 32:48 C]
  int bc = blockIdx.x >> 1;                       // b*NCH + c
  int d  = ((blockIdx.x & 1) << 8) + threadIdx.x;
  int b = bc >> 7, c = bc & (NCH-1);
  int t0 = b*LL + c*CHUNK;
  int tid = threadIdx.x;
  if (tid < CHUNK*12) {
    int row = tid / 12, q = tid - row*12;
    *(float4*)&DBC[row][q*4] = *(const float4*)&xdbl[(size_t)(t0+row)*XDIM + q*4];
  }
  __syncthreads();
  float4 wq[4];
  #pragma unroll
  for (int i = 0; i < 4; ++i) wq[i] = *(const float4*)&dtw[(size_t)d*RDT + i*4];
  float dtbv = dtb[d];
  float Dpv = Dp[d];
  float A[NST];
  #pragma unroll
  for (int n = 0; n < NST; ++n) A[n] = -__expf(A_log[d*NST + n]);
  float A0 = A[0];
  bool geo = true;
  #pragma unroll
  for (int n = 1; n < NST; ++n) {
    float ideal = A0 * (float)(n+1);
    geo = geo && (fabsf(A[n] - ideal) <= 1e-5f * fabsf(ideal));
  }
  float h[NST];
  #pragma unroll
  for (int n = 0; n < NST; ++n) h[n] = 0.f;
  float ds = 0.f;
  for (int l = 0; l < CHUNK; ++l) {
    int t = t0 + l;
    float xcv = (float)xc[(size_t)t*DI + d];
    float acc = dtbv;
    #pragma unroll
    for (int i = 0; i < 4; ++i) {
      float4 a = *(const float4*)&DBC[l][i*4];
      acc = fmaf(a.x, wq[i].x, acc); acc = fmaf(a.y, wq[i].y, acc);
      acc = fmaf(a.z, wq[i].z, acc); acc = fmaf(a.w, wq[i].w, acc);
    }
    float del = fmaxf(acc, 0.f) + log1pf(__expf(-fabsf(acc)));
    ds += del;
    float dx = del * xcv;
    float yv = 0.f;
    if (geo) {
      float e = __expf(del * A0);
      float dA = e;
      h[0] = fmaf(dA, h[0], dx * DBC[l][16]);
      yv = fmaf(h[0], DBC[l][32], yv);
      #pragma unroll
      for (int n = 1; n < NST; ++n) {
        dA *= e;
        h[n] = fmaf(dA, h[n], dx * DBC[l][16 + n]);
        yv = fmaf(h[n], DBC[l][32 + n], yv);
      }
    } else {
      #pragma unroll
      for (int n = 0; n < NST; ++n) {
        h[n] = fmaf(__expf(del * A[n]), h[n], dx * DBC[l][16 + n]);
        yv = fmaf(h[n], DBC[l][32 + n], yv);
      }
    }
    yv = fmaf(Dpv, xcv, yv);
    ylocal[(size_t)t*DI + d] = yv;
    csout[(size_t)t*DI + d] = ds;
  }
  #pragma unroll
  for (int n = 0; n < NST; ++n)
    hloc[((size_t)(b*NST + n)*NCH + c)*DI + d] = h[n];
  dsum[(size_t)bc*DI + d] = ds;
}

// 256 blocks x 64 thr: one wave per block spreads the serial chains over all CUs.
__global__ __launch_bounds__(64) void scan_pass2(
    const float* __restrict__ hloc, const float* __restrict__ dsum,
    const float* __restrict__ A_log, float* __restrict__ hinit) {
  int g = blockIdx.x*64 + threadIdx.x;
  int d = g & (DI-1);
  int n = (g >> 9) & (NST-1);
  int b = g >> 13;
  float A = -__expf(A_log[d*NST + n]);
  float hc = 0.f;
  size_t base = (size_t)(b*NST + n)*NCH*DI + d;
  #pragma unroll 4
  for (int c = 0; c < NCH; ++c) {
    hinit[base + (size_t)c*DI] = hc;
    float P = __expf(A * dsum[(size_t)(b*NCH + c)*DI + d]);
    hc = fmaf(P, hc, hloc[base + (size_t)c*DI]);
  }
}

// pass3: fully parallel correction + gate.  y = (ylocal + sum_n C*G*hinit)*zg.
__global__ __launch_bounds__(256) void scan_pass3(
    const float* __restrict__ cs, const float* __restrict__ ylocal,
    const __bf16* __restrict__ zg, const float* __restrict__ xdbl,
    const float* __restrict__ A_log, const float* __restrict__ hinit,
    __bf16* __restrict__ y) {
  __shared__ __align__(16) float Cs[CHUNK][16];
  int bc = blockIdx.x >> 1;
  int d  = ((blockIdx.x & 1) << 8) + threadIdx.x;
  int b = bc >> 7, c = bc & (NCH-1);
  int t0 = b*LL + c*CHUNK;
  int tid = threadIdx.x;
  if (tid < CHUNK*4) {
    int row = tid >> 2, q = tid & 3;
    *(float4*)&Cs[row][q*4] = *(const float4*)&xdbl[(size_t)(t0+row)*XDIM + 32 + q*4];
  }
  __syncthreads();
  float A[NST];
  #pragma unroll
  for (int n = 0; n < NST; ++n) A[n] = -__expf(A_log[d*NST + n]);
  float A0 = A[0];
  bool geo = true;
  #pragma unroll
  for (int n = 1; n < NST; ++n) {
    float ideal = A0 * (float)(n+1);
    geo = geo && (fabsf(A[n] - ideal) <= 1e-5f * fabsf(ideal));
  }
  float hin[NST];
  #pragma unroll
  for (int n = 0; n < NST; ++n) hin[n] = hinit[((size_t)(b*NST + n)*NCH + c)*DI + d];
  for (int l = 0; l < CHUNK; ++l) {
    int t = t0 + l;
    float csv = cs[(size_t)t*DI + d];
    float ylv = ylocal[(size_t)t*DI + d];
    float zvg = (float)zg[(size_t)t*DI + d];
    float corr = 0.f;
    if (geo) {
      float g = __expf(csv * A0);
      float dA = g;
      corr = hin[0] * dA * Cs[l][0];
      #pragma unroll
      for (int n = 1; n < NST; ++n) {
        dA *= g;
        corr = fmaf(hin[n] * dA, Cs[l][n], corr);
      }
    } else {
      #pragma unroll
      for (int n = 0; n < NST; ++n)
        corr = fmaf(hin[n] * __expf(A[n] * csv), Cs[l][n], corr);
    }
    y[(size_t)t*DI + d] = (__bf16)((ylv + corr) * zvg);
  }
}

// ---------------- pool stage 1: partial sums over L (256 blocks) ----------------
__global__ void pool1_kernel(const float* __restrict__ ln, float* __restrict__ part) {
  int blk = blockIdx.x;             // b*128 + c
  int b = blk >> 7, c = blk & 127;
  int d = threadIdx.x;
  const float* base = ln + (size_t)b*LL*DM + (size_t)c*16*DM + d;
  float s = 0.f;
  #pragma unroll
  for (int l = 0; l < 16; ++l) s += base[(size_t)l*DM];
  part[(size_t)blk*DM + d] = s;
}

// ---------------- pool stage 2 + decode ----------------
__global__ void pool_decode_kernel(const float* __restrict__ part, const float* __restrict__ dw,
                                   const float* __restrict__ db, float* __restrict__ out) {
  int b = blockIdx.x, d = threadIdx.x;
  __shared__ float pooled[DM];
  float s = 0.f;
  for (int c = 0; c < 128; ++c) s += part[(size_t)(b*128 + c)*DM + d];
  pooled[d] = s * (1.0f/LL);
  __syncthreads();
  if (d < DOUT) {
    float acc = db[d];
    for (int m = 0; m < DM; ++m) acc = fmaf(pooled[m], dw[d*DM + m], acc);
    out[b*DOUT + d] = acc;
  }
}

extern "C" void kernel_launch(void* const* d_in, const int* in_sizes, int n_in,
                              void* d_out, int out_size, void* d_ws, size_t ws_size,
                              hipStream_t stream) {
  const int*   ids     = (const int*)d_in[0];
  const float* emb     = (const float*)d_in[1];
  const float* norm_w  = (const float*)d_in[2];
  const float* norm_b  = (const float*)d_in[3];
  const float* in_w    = (const float*)d_in[4];
  const float* conv_w  = (const float*)d_in[5];
  const float* conv_b  = (const float*)d_in[6];
  const float* xp_w    = (const float*)d_in[7];
  const float* dt_w    = (const float*)d_in[8];
  const float* dt_b    = (const float*)d_in[9];
  const float* A_log   = (const float*)d_in[10];
  const float* Dp      = (const float*)d_in[11];
  const float* out_w   = (const float*)d_in[12];
  const float* normf_w = (const float*)d_in[13];
  const float* normf_b = (const float*)d_in[14];
  const float* dec_w   = (const float*)d_in[15];
  const float* dec_b   = (const float*)d_in[16];
  float* out = (float*)d_out;

  float* ws = (float*)d_ws;
  float* hidden   = ws; ws += TOK*DM;
  float* residual = ws; ws += TOK*DM;
  float* hbuf     = ws; ws += TOK*DM;
  float* xdblbuf  = ws; ws += TOK*XDIM;
  float* hlocbuf  = ws; ws += (size_t)BB*NCH*NST*DI;
  float* hinitbuf = ws; ws += (size_t)BB*NCH*NST*DI;
  float* dsumbuf  = ws; ws += (size_t)BB*NCH*DI;
  float* partbuf  = ws; ws += (size_t)BB*128*DM;
  float* csbuf    = ws; ws += (size_t)TOK*DI;
  float* ylbuf    = ws; ws += (size_t)TOK*DI;
  __bf16* xmbuf   = (__bf16*)ws; ws += TOK*DI/2;
  __bf16* zgbuf   = (__bf16*)ws; ws += TOK*DI/2;
  __bf16* xcbuf   = (__bf16*)ws; ws += TOK*DI/2;
  __bf16* hbuf_bf = (__bf16*)ws; ws += TOK*DM/2;
  __bf16* ybuf_bf = (__bf16*)ws; ws += TOK*DI/2;
  __bf16* inw_bf  = (__bf16*)ws; ws += (size_t)NLAY*2*DI*DM/2;
  __bf16* outw_bf = (__bf16*)ws; ws += (size_t)NLAY*DM*DI/2;
  __bf16* xpw_bf  = (__bf16*)ws; ws += (size_t)NLAY*XDIM*DI/2 + 256;

  const int n_inw = NLAY*2*DI*DM, n_outw = NLAY*DM*DI, n_xpw = NLAY*XDIM*DI;
  cast_w_kernel<<<2048, 256, 0, stream>>>(in_w, out_w, xp_w, inw_bf, outw_bf, xpw_bf,
                                          n_inw, n_outw, n_xpw);

  for (int i = 0; i < NLAY; ++i) {
    add_ln_kernel<<<TOK, DM, 0, stream>>>(residual, hidden, ids, emb,
                                          norm_w + i*DM, norm_b + i*DM,
                                          hbuf, hbuf_bf, i == 0, 0);
    gemm_in_d<<<dim3(2, TOK/16), 512, 0, stream>>>(
        hbuf_bf, inw_bf + (size_t)i*2*DI*DM, xmbuf, zgbuf);
    xproj16<<<TOK/16, 512, 0, stream>>>(
        xmbuf, conv_w + i*DI*KC, conv_b + i*DI,
        xpw_bf + (size_t)i*XDIM*DI, xdblbuf, xcbuf);
    scan_pass1<<<BB*NCH*(DI/256), 256, 0, stream>>>(
        xcbuf, xdblbuf,
        dt_w + (size_t)i*DI*RDT, dt_b + i*DI, A_log + (size_t)i*DI*NST,
        Dp + i*DI, hlocbuf, dsumbuf, ylbuf, csbuf);
    scan_pass2<<<(BB*NST*DI)/64, 64, 0, stream>>>(
        hlocbuf, dsumbuf, A_log + (size_t)i*DI*NST, hinitbuf);
    scan_pass3<<<BB*NCH*(DI/256), 256, 0, stream>>>(
        csbuf, ylbuf, zgbuf, xdblbuf, A_log + (size_t)i*DI*NST,
        hinitbuf, ybuf_bf);
    gemm_out_d<<<dim3(2, TOK/16), 256, 0, stream>>>(
        ybuf_bf, outw_bf + (size_t)i*DM*DI, hidden);
  }

  add_ln_kernel<<<TOK, DM, 0, stream>>>(residual, hidden, ids, emb,
                                        normf_w, normf_b, hbuf, hbuf_bf, 0, 1);
  pool1_kernel<<<BB*128, DM, 0, stream>>>(hbuf, partbuf);
  pool_decode_kernel<<<BB, DM, 0, stream>>>(partbuf, dec_w, dec_b, out);
}

// Round 8
// 417.421 us; speedup vs baseline: 1.1548x; 1.1548x over previous
//
#include <hip/hip_runtime.h>
#include <hip/hip_bf16.h>

#define BB 2
#define LL 2048
#define DM 256
#define DI 512
#define NST 16
#define RDT 16
#define KC 4
#define NLAY 4
#define DOUT 10
#define XDIM 48            // R + 2N
#define TOK (BB*LL)        // 4096
#define EPSF 1e-5f
#define CHUNK 16
#define NCH (LL/CHUNK)     // 128

typedef __bf16 bf16x8 __attribute__((ext_vector_type(8)));
typedef __bf16 bf16x4 __attribute__((ext_vector_type(4)));
typedef float  f32x4  __attribute__((ext_vector_type(4)));

__device__ __forceinline__ float sigmoid_f(float x) { return 1.0f / (1.0f + __expf(-x)); }

// ---------------- weight cast fp32 -> bf16 (once per call) ----------------
__global__ void cast_w_kernel(const float* __restrict__ a, const float* __restrict__ b,
                              const float* __restrict__ c,
                              __bf16* __restrict__ ab, __bf16* __restrict__ bb,
                              __bf16* __restrict__ cbf,
                              int na, int nb, int nc) {
  int stride = gridDim.x * 256;
  for (int i = blockIdx.x*256 + threadIdx.x; i < na; i += stride) ab[i] = (__bf16)a[i];
  for (int i = blockIdx.x*256 + threadIdx.x; i < nb; i += stride) bb[i] = (__bf16)b[i];
  for (int i = blockIdx.x*256 + threadIdx.x; i < nc; i += stride) cbf[i] = (__bf16)c[i];
}

// ------- residual add + layernorm; first layer reads embedding directly -------
__global__ void add_ln_kernel(float* __restrict__ residual, const float* __restrict__ hidden,
                              const int* __restrict__ ids, const float* __restrict__ emb,
                              const float* __restrict__ w, const float* __restrict__ bia,
                              float* __restrict__ out, __bf16* __restrict__ out_bf,
                              int first, int write32) {
  int t = blockIdx.x, d = threadIdx.x;
  __shared__ float ws8[8];
  float r;
  if (first) r = emb[ids[t]*DM + d];
  else       r = hidden[t*DM + d] + residual[t*DM + d];
  residual[t*DM + d] = r;
  float s = r;
  #pragma unroll
  for (int o = 32; o; o >>= 1) s += __shfl_down(s, o);
  if ((d & 63) == 0) ws8[d >> 6] = s;
  __syncthreads();
  float mean = (ws8[0] + ws8[1] + ws8[2] + ws8[3]) * (1.0f/DM);
  float diff = r - mean;
  float q = diff * diff;
  #pragma unroll
  for (int o = 32; o; o >>= 1) q += __shfl_down(q, o);
  if ((d & 63) == 0) ws8[4 + (d >> 6)] = q;
  __syncthreads();
  float var = (ws8[4] + ws8[5] + ws8[6] + ws8[7]) * (1.0f/DM);
  float v = diff * rsqrtf(var + EPSF) * w[d] + bia[d];
  if (write32) out[t*DM + d] = v;
  out_bf[t*DM + d] = (__bf16)v;
}

// ---------------- bf16 MFMA GEMM (in_proj): tile M=64, E=128 ----------------
// cols<512 -> xm bf16; cols>=512 -> zg = silu(z) bf16.  (R5-verified)
__global__ __launch_bounds__(256, 2) void gemm_in_bf16(const __bf16* __restrict__ A,
                                                       const __bf16* __restrict__ W,
                                                       __bf16* __restrict__ xm,
                                                       __bf16* __restrict__ zg) {
  __shared__ __bf16 As[4*64*8];
  __shared__ __bf16 Ws[8*64*8];
  const int K = DM;
  int tid = threadIdx.x;
  int lane = tid & 63, wv = tid >> 6;
  int bm = blockIdx.y * 64, be = blockIdx.x * 128;
  int ss = tid >> 6, sq = (tid >> 4) & 3, sm = tid & 15;
  f32x4 acc[8];
  #pragma unroll
  for (int et = 0; et < 8; ++et) acc[et] = (f32x4){0.f, 0.f, 0.f, 0.f};
  for (int k0 = 0; k0 < K; k0 += 32) {
    bf16x8 av = *(const bf16x8*)&A[(size_t)(bm + ss*16 + sm)*K + k0 + sq*8];
    bf16x8 w0 = *(const bf16x8*)&W[(size_t)(be + ss*16 + sm)*K + k0 + sq*8];
    bf16x8 w1 = *(const bf16x8*)&W[(size_t)(be + 64 + ss*16 + sm)*K + k0 + sq*8];
    __syncthreads();
    *(bf16x8*)&As[((ss*4 + sq)*16 + sm)*8] = av;
    *(bf16x8*)&Ws[((ss*4 + sq)*16 + sm)*8] = w0;
    *(bf16x8*)&Ws[(((4 + ss)*4 + sq)*16 + sm)*8] = w1;
    __syncthreads();
    bf16x8 af = *(const bf16x8*)&As[(wv*64 + lane)*8];
    #pragma unroll
    for (int et = 0; et < 8; ++et) {
      bf16x8 bfr = *(const bf16x8*)&Ws[(et*64 + lane)*8];
      acc[et] = __builtin_amdgcn_mfma_f32_16x16x32_bf16(af, bfr, acc[et], 0, 0, 0);
    }
  }
  int row0 = bm + wv*16 + (lane >> 4)*4;
  int colb = lane & 15;
  #pragma unroll
  for (int et = 0; et < 8; ++et) {
    int col = be + et*16 + colb;
    if (col < DI) {
      #pragma unroll
      for (int r = 0; r < 4; ++r)
        xm[(size_t)(row0 + r)*DI + col] = (__bf16)acc[et][r];
    } else {
      #pragma unroll
      for (int r = 0; r < 4; ++r) {
        float zv = acc[et][r];
        zg[(size_t)(row0 + r)*DI + col - DI] = (__bf16)(zv * sigmoid_f(zv));
      }
    }
  }
}

// ---------------- bf16 MFMA GEMM (out_proj): tile M=64, E=64, fp32 C ----------------
__global__ __launch_bounds__(256, 2) void gemm_out_bf16(const __bf16* __restrict__ A,
                                                        const __bf16* __restrict__ W,
                                                        float* __restrict__ C) {
  __shared__ __bf16 As[4*64*8];
  __shared__ __bf16 Ws[4*64*8];
  const int K = DI, E = DM;
  int tid = threadIdx.x;
  int lane = tid & 63, wv = tid >> 6;
  int bm = blockIdx.y * 64, be = blockIdx.x * 64;
  int ss = tid >> 6, sq = (tid >> 4) & 3, sm = tid & 15;
  f32x4 acc[4];
  #pragma unroll
  for (int et = 0; et < 4; ++et) acc[et] = (f32x4){0.f, 0.f, 0.f, 0.f};
  for (int k0 = 0; k0 < K; k0 += 32) {
    bf16x8 av = *(const bf16x8*)&A[(size_t)(bm + ss*16 + sm)*K + k0 + sq*8];
    bf16x8 wvv = *(const bf16x8*)&W[(size_t)(be + ss*16 + sm)*K + k0 + sq*8];
    __syncthreads();
    *(bf16x8*)&As[((ss*4 + sq)*16 + sm)*8] = av;
    *(bf16x8*)&Ws[((ss*4 + sq)*16 + sm)*8] = wvv;
    __syncthreads();
    bf16x8 af = *(const bf16x8*)&As[(wv*64 + lane)*8];
    #pragma unroll
    for (int et = 0; et < 4; ++et) {
      bf16x8 bfr = *(const bf16x8*)&Ws[(et*64 + lane)*8];
      acc[et] = __builtin_amdgcn_mfma_f32_16x16x32_bf16(af, bfr, acc[et], 0, 0, 0);
    }
  }
  int row0 = bm + wv*16 + (lane >> 4)*4;
  int col0 = be + (lane & 15);
  #pragma unroll
  for (int et = 0; et < 4; ++et)
    #pragma unroll
    for (int r = 0; r < 4; ++r)
      C[(size_t)(row0 + r)*E + col0 + et*16] = acc[et][r];
}

// ------- fused x_proj + scan pass1: one 16-token chunk per block, 512 thr -------
// Phase A (xproj16 logic, 8 waves split K): conv+silu -> xc kept in LDS
// (XOR-swizzled), MFMA for x_dbl, cross-wave reduce -> DBC tile in LDS
// (+ global xdbl write for pass3's C rows).
// Phase B (scan_pass1 logic, d = tid over all 512 channels): serial 16-step
// scan reading xc/DBC straight from LDS. No xc global round-trip (8MB/layer),
// one launch instead of two.
__global__ __launch_bounds__(512) void xproj_scan1(
    const __bf16* __restrict__ xm, const float* __restrict__ cw,
    const float* __restrict__ cb, const __bf16* __restrict__ Wbf,
    const float* __restrict__ dtw, const float* __restrict__ dtb,
    const float* __restrict__ A_log, const float* __restrict__ Dp,
    float* __restrict__ xdbl, float* __restrict__ hloc,
    float* __restrict__ dsum, float* __restrict__ ylocal,
    float* __restrict__ csout) {
  __shared__ float red[8][3][16][16];           // 24 KB
  __shared__ __bf16 xc_s[CHUNK][DI];            // 16 KB, cols XOR-swizzled
  __shared__ __align__(16) float DBC[CHUNK][48];// 3 KB  [l][dt|B|C]
  int tid = threadIdx.x;
  int lane = tid & 63, w = tid >> 6;            // 8 waves
  int bc = blockIdx.x;                          // chunk id; t0 = bc*16
  int t0 = bc * CHUNK;
  int b = bc >> 7, c = bc & (NCH - 1);
  int r16 = lane & 15;
  int row = t0 + r16;
  int l = row & (LL - 1);
  int kg = (lane >> 4) * 8;

  // ---- phase A: conv+silu + x_proj MFMA ----
  f32x4 acc[3];
  #pragma unroll
  for (int e = 0; e < 3; ++e) acc[e] = (f32x4){0.f, 0.f, 0.f, 0.f};
  #pragma unroll
  for (int ks = 0; ks < 2; ++ks) {
    int ch = w*64 + ks*32 + kg;
    bf16x8 v0 = *(const bf16x8*)&xm[(size_t)row*DI + ch];
    bf16x8 v1 = (l >= 1) ? *(const bf16x8*)&xm[(size_t)(row-1)*DI + ch] : (bf16x8)(__bf16)0;
    bf16x8 v2 = (l >= 2) ? *(const bf16x8*)&xm[(size_t)(row-2)*DI + ch] : (bf16x8)(__bf16)0;
    bf16x8 v3 = (l >= 3) ? *(const bf16x8*)&xm[(size_t)(row-3)*DI + ch] : (bf16x8)(__bf16)0;
    bf16x8 a8;
    #pragma unroll
    for (int j = 0; j < 8; ++j) {
      float4 cwv = *(const float4*)&cw[(ch + j)*KC];
      float cv = cb[ch + j];
      cv = fmaf(cwv.x, (float)v3[j], cv);
      cv = fmaf(cwv.y, (float)v2[j], cv);
      cv = fmaf(cwv.z, (float)v1[j], cv);
      cv = fmaf(cwv.w, (float)v0[j], cv);
      a8[j] = (__bf16)(cv * sigmoid_f(cv));
    }
    *(bf16x8*)&xc_s[r16][ch ^ ((r16 & 7) << 3)] = a8;   // swizzled LDS store
    #pragma unroll
    for (int e = 0; e < 3; ++e) {
      bf16x8 bv = *(const bf16x8*)&Wbf[(size_t)(e*16 + r16)*DI + ch];
      acc[e] = __builtin_amdgcn_mfma_f32_16x16x32_bf16(a8, bv, acc[e], 0, 0, 0);
    }
  }
  #pragma unroll
  for (int e = 0; e < 3; ++e)
    #pragma unroll
    for (int r = 0; r < 4; ++r)
      red[w][e][(lane >> 4)*4 + r][r16] = acc[e][r];
  __syncthreads();
  for (int idx = tid; idx < 768; idx += 512) {
    int e = idx >> 8, rr = (idx >> 4) & 15, cc = idx & 15;
    float s = 0.f;
    #pragma unroll
    for (int w8 = 0; w8 < 8; ++w8) s += red[w8][e][rr][cc];
    DBC[rr][e*16 + cc] = s;
    xdbl[(size_t)(t0 + rr)*XDIM + e*16 + cc] = s;  // pass3 reads the C rows
  }
  __syncthreads();

  // ---- phase B: serial 16-step scan, d = tid (all 512 channels) ----
  int d = tid;
  float4 wq[4];
  #pragma unroll
  for (int i = 0; i < 4; ++i) wq[i] = *(const float4*)&dtw[(size_t)d*RDT + i*4];
  float dtbv = dtb[d];
  float Dpv = Dp[d];
  float A[NST];
  #pragma unroll
  for (int n = 0; n < NST; ++n) A[n] = -__expf(A_log[d*NST + n]);
  float A0 = A[0];
  bool geo = true;
  #pragma unroll
  for (int n = 1; n < NST; ++n) {
    float ideal = A0 * (float)(n+1);
    geo = geo && (fabsf(A[n] - ideal) <= 1e-5f * fabsf(ideal));
  }
  float h[NST];
  #pragma unroll
  for (int n = 0; n < NST; ++n) h[n] = 0.f;
  float ds = 0.f;
  for (int lp = 0; lp < CHUNK; ++lp) {
    int t = t0 + lp;
    float xcv = (float)xc_s[lp][d ^ ((lp & 7) << 3)];
    float acs = dtbv;
    #pragma unroll
    for (int i = 0; i < 4; ++i) {
      float4 a = *(const float4*)&DBC[lp][i*4];
      acs = fmaf(a.x, wq[i].x, acs); acs = fmaf(a.y, wq[i].y, acs);
      acs = fmaf(a.z, wq[i].z, acs); acs = fmaf(a.w, wq[i].w, acs);
    }
    float del = fmaxf(acs, 0.f) + log1pf(__expf(-fabsf(acs)));
    ds += del;
    float dx = del * xcv;
    float yv = 0.f;
    if (geo) {
      float e = __expf(del * A0);
      float dA = e;
      h[0] = fmaf(dA, h[0], dx * DBC[lp][16]);
      yv = fmaf(h[0], DBC[lp][32], yv);
      #pragma unroll
      for (int n = 1; n < NST; ++n) {
        dA *= e;
        h[n] = fmaf(dA, h[n], dx * DBC[lp][16 + n]);
        yv = fmaf(h[n], DBC[lp][32 + n], yv);
      }
    } else {
      #pragma unroll
      for (int n = 0; n < NST; ++n) {
        h[n] = fmaf(__expf(del * A[n]), h[n], dx * DBC[lp][16 + n]);
        yv = fmaf(h[n], DBC[lp][32 + n], yv);
      }
    }
    yv = fmaf(Dpv, xcv, yv);
    ylocal[(size_t)t*DI + d] = yv;
    csout[(size_t)t*DI + d] = ds;
  }
  #pragma unroll
  for (int n = 0; n < NST; ++n)
    hloc[((size_t)(b*NST + n)*NCH + c)*DI + d] = h[n];
  dsum[(size_t)bc*DI + d] = ds;
}

// 256 blocks x 64 thr: spreads the 16K serial chains over all CUs.
__global__ __launch_bounds__(64) void scan_pass2(
    const float* __restrict__ hloc, const float* __restrict__ dsum,
    const float* __restrict__ A_log, float* __restrict__ hinit) {
  int g = blockIdx.x*64 + threadIdx.x;
  int d = g & (DI-1);
  int n = (g >> 9) & (NST-1);
  int b = g >> 13;
  float A = -__expf(A_log[d*NST + n]);
  float hc = 0.f;
  size_t base = (size_t)(b*NST + n)*NCH*DI + d;
  #pragma unroll 4
  for (int c = 0; c < NCH; ++c) {
    hinit[base + (size_t)c*DI] = hc;
    float P = __expf(A * dsum[(size_t)(b*NCH + c)*DI + d]);
    hc = fmaf(P, hc, hloc[base + (size_t)c*DI]);
  }
}

// pass3: fully parallel correction + gate.  y = (ylocal + sum_n C*G*hinit)*zg.
__global__ __launch_bounds__(256) void scan_pass3(
    const float* __restrict__ cs, const float* __restrict__ ylocal,
    const __bf16* __restrict__ zg, const float* __restrict__ xdbl,
    const float* __restrict__ A_log, const float* __restrict__ hinit,
    __bf16* __restrict__ y) {
  __shared__ __align__(16) float Cs[CHUNK][16];
  int bc = blockIdx.x >> 1;
  int d  = ((blockIdx.x & 1) << 8) + threadIdx.x;
  int b = bc >> 7, c = bc & (NCH-1);
  int t0 = b*LL + c*CHUNK;
  int tid = threadIdx.x;
  if (tid < CHUNK*4) {
    int row = tid >> 2, q = tid & 3;
    *(float4*)&Cs[row][q*4] = *(const float4*)&xdbl[(size_t)(t0+row)*XDIM + 32 + q*4];
  }
  __syncthreads();
  float A[NST];
  #pragma unroll
  for (int n = 0; n < NST; ++n) A[n] = -__expf(A_log[d*NST + n]);
  float A0 = A[0];
  bool geo = true;
  #pragma unroll
  for (int n = 1; n < NST; ++n) {
    float ideal = A0 * (float)(n+1);
    geo = geo && (fabsf(A[n] - ideal) <= 1e-5f * fabsf(ideal));
  }
  float hin[NST];
  #pragma unroll
  for (int n = 0; n < NST; ++n) hin[n] = hinit[((size_t)(b*NST + n)*NCH + c)*DI + d];
  for (int l = 0; l < CHUNK; ++l) {
    int t = t0 + l;
    float csv = cs[(size_t)t*DI + d];
    float ylv = ylocal[(size_t)t*DI + d];
    float zvg = (float)zg[(size_t)t*DI + d];
    float corr = 0.f;
    if (geo) {
      float g = __expf(csv * A0);
      float dA = g;
      corr = hin[0] * dA * Cs[l][0];
      #pragma unroll
      for (int n = 1; n < NST; ++n) {
        dA *= g;
        corr = fmaf(hin[n] * dA, Cs[l][n], corr);
      }
    } else {
      #pragma unroll
      for (int n = 0; n < NST; ++n)
        corr = fmaf(hin[n] * __expf(A[n] * csv), Cs[l][n], corr);
    }
    y[(size_t)t*DI + d] = (__bf16)((ylv + corr) * zvg);
  }
}

// ---------------- pool stage 1: partial sums over L (256 blocks) ----------------
__global__ void pool1_kernel(const float* __restrict__ ln, float* __restrict__ part) {
  int blk = blockIdx.x;             // b*128 + c
  int b = blk >> 7, c = blk & 127;
  int d = threadIdx.x;
  const float* base = ln + (size_t)b*LL*DM + (size_t)c*16*DM + d;
  float s = 0.f;
  #pragma unroll
  for (int l = 0; l < 16; ++l) s += base[(size_t)l*DM];
  part[(size_t)blk*DM + d] = s;
}

// ---------------- pool stage 2 + decode ----------------
__global__ void pool_decode_kernel(const float* __restrict__ part, const float* __restrict__ dw,
                                   const float* __restrict__ db, float* __restrict__ out) {
  int b = blockIdx.x, d = threadIdx.x;
  __shared__ float pooled[DM];
  float s = 0.f;
  for (int c = 0; c < 128; ++c) s += part[(size_t)(b*128 + c)*DM + d];
  pooled[d] = s * (1.0f/LL);
  __syncthreads();
  if (d < DOUT) {
    float acc = db[d];
    for (int m = 0; m < DM; ++m) acc = fmaf(pooled[m], dw[d*DM + m], acc);
    out[b*DOUT + d] = acc;
  }
}

extern "C" void kernel_launch(void* const* d_in, const int* in_sizes, int n_in,
                              void* d_out, int out_size, void* d_ws, size_t ws_size,
                              hipStream_t stream) {
  const int*   ids     = (const int*)d_in[0];
  const float* emb     = (const float*)d_in[1];
  const float* norm_w  = (const float*)d_in[2];
  const float* norm_b  = (const float*)d_in[3];
  const float* in_w    = (const float*)d_in[4];
  const float* conv_w  = (const float*)d_in[5];
  const float* conv_b  = (const float*)d_in[6];
  const float* xp_w    = (const float*)d_in[7];
  const float* dt_w    = (const float*)d_in[8];
  const float* dt_b    = (const float*)d_in[9];
  const float* A_log   = (const float*)d_in[10];
  const float* Dp      = (const float*)d_in[11];
  const float* out_w   = (const float*)d_in[12];
  const float* normf_w = (const float*)d_in[13];
  const float* normf_b = (const float*)d_in[14];
  const float* dec_w   = (const float*)d_in[15];
  const float* dec_b   = (const float*)d_in[16];
  float* out = (float*)d_out;

  float* ws = (float*)d_ws;
  float* hidden   = ws; ws += TOK*DM;
  float* residual = ws; ws += TOK*DM;
  float* hbuf     = ws; ws += TOK*DM;
  float* xdblbuf  = ws; ws += TOK*XDIM;
  float* hlocbuf  = ws; ws += (size_t)BB*NCH*NST*DI;
  float* hinitbuf = ws; ws += (size_t)BB*NCH*NST*DI;
  float* dsumbuf  = ws; ws += (size_t)BB*NCH*DI;
  float* partbuf  = ws; ws += (size_t)BB*128*DM;
  float* csbuf    = ws; ws += (size_t)TOK*DI;
  float* ylbuf    = ws; ws += (size_t)TOK*DI;
  __bf16* xmbuf   = (__bf16*)ws; ws += TOK*DI/2;
  __bf16* zgbuf   = (__bf16*)ws; ws += TOK*DI/2;
  __bf16* hbuf_bf = (__bf16*)ws; ws += TOK*DM/2;
  __bf16* ybuf_bf = (__bf16*)ws; ws += TOK*DI/2;
  __bf16* inw_bf  = (__bf16*)ws; ws += (size_t)NLAY*2*DI*DM/2;
  __bf16* outw_bf = (__bf16*)ws; ws += (size_t)NLAY*DM*DI/2;
  __bf16* xpw_bf  = (__bf16*)ws; ws += (size_t)NLAY*XDIM*DI/2 + 256;

  const int n_inw = NLAY*2*DI*DM, n_outw = NLAY*DM*DI, n_xpw = NLAY*XDIM*DI;
  cast_w_kernel<<<2048, 256, 0, stream>>>(in_w, out_w, xp_w, inw_bf, outw_bf, xpw_bf,
                                          n_inw, n_outw, n_xpw);

  for (int i = 0; i < NLAY; ++i) {
    add_ln_kernel<<<TOK, DM, 0, stream>>>(residual, hidden, ids, emb,
                                          norm_w + i*DM, norm_b + i*DM,
                                          hbuf, hbuf_bf, i == 0, 0);
    gemm_in_bf16<<<dim3((2*DI)/128, TOK/64), 256, 0, stream>>>(
        hbuf_bf, inw_bf + (size_t)i*2*DI*DM, xmbuf, zgbuf);
    xproj_scan1<<<TOK/CHUNK, 512, 0, stream>>>(
        xmbuf, conv_w + i*DI*KC, conv_b + i*DI,
        xpw_bf + (size_t)i*XDIM*DI,
        dt_w + (size_t)i*DI*RDT, dt_b + i*DI, A_log + (size_t)i*DI*NST,
        Dp + i*DI, xdblbuf, hlocbuf, dsumbuf, ylbuf, csbuf);
    scan_pass2<<<(BB*NST*DI)/64, 64, 0, stream>>>(
        hlocbuf, dsumbuf, A_log + (size_t)i*DI*NST, hinitbuf);
    scan_pass3<<<BB*NCH*(DI/256), 256, 0, stream>>>(
        csbuf, ylbuf, zgbuf, xdblbuf, A_log + (size_t)i*DI*NST,
        hinitbuf, ybuf_bf);
    gemm_out_bf16<<<dim3(DM/64, TOK/64), 256, 0, stream>>>(
        ybuf_bf, outw_bf + (size_t)i*DM*DI, hidden);
  }

  add_ln_kernel<<<TOK, DM, 0, stream>>>(residual, hidden, ids, emb,
                                        normf_w, normf_b, hbuf, hbuf_bf, 0, 1);
  pool1_kernel<<<BB*128, DM, 0, stream>>>(hbuf, partbuf);
  pool_decode_kernel<<<BB, DM, 0, stream>>>(partbuf, dec_w, dec_b, out);
}

// Round 9
// 370.421 us; speedup vs baseline: 1.3013x; 1.1269x over previous
//
#include <hip/hip_runtime.h>
#include <hip/hip_bf16.h>

#define BB 2
#define LL 2048
#define DM 256
#define DI 512
#define NST 16
#define RDT 16
#define KC 4
#define NLAY 4
#define DOUT 10
#define XDIM 48            // R + 2N
#define TOK (BB*LL)        // 4096
#define EPSF 1e-5f
#define CHUNK 16
#define NCH (LL/CHUNK)     // 128

typedef __bf16 bf16x8 __attribute__((ext_vector_type(8)));
typedef __bf16 bf16x4 __attribute__((ext_vector_type(4)));
typedef float  f32x4  __attribute__((ext_vector_type(4)));

__device__ __forceinline__ float sigmoid_f(float x) { return 1.0f / (1.0f + __expf(-x)); }

// ---------------- weight cast fp32 -> bf16 (once per call) ----------------
__global__ void cast_w_kernel(const float* __restrict__ a, const float* __restrict__ b,
                              const float* __restrict__ c,
                              __bf16* __restrict__ ab, __bf16* __restrict__ bb,
                              __bf16* __restrict__ cbf,
                              int na, int nb, int nc) {
  int stride = gridDim.x * 256;
  for (int i = blockIdx.x*256 + threadIdx.x; i < na; i += stride) ab[i] = (__bf16)a[i];
  for (int i = blockIdx.x*256 + threadIdx.x; i < nb; i += stride) bb[i] = (__bf16)b[i];
  for (int i = blockIdx.x*256 + threadIdx.x; i < nc; i += stride) cbf[i] = (__bf16)c[i];
}

// ------- residual add + layernorm, wave-per-token: no barriers, no LDS -------
// 4 tokens/block (4 waves x 64 lanes x float4). Grid = TOK/4.
__global__ void add_ln_kernel(float* __restrict__ residual, const float* __restrict__ hidden,
                              const int* __restrict__ ids, const float* __restrict__ emb,
                              const float* __restrict__ w, const float* __restrict__ bia,
                              float* __restrict__ out, __bf16* __restrict__ out_bf,
                              int first, int write32) {
  int wv = threadIdx.x >> 6, lane = threadIdx.x & 63;
  int t = blockIdx.x*4 + wv;
  float4 rv;
  if (first) {
    rv = *(const float4*)&emb[(size_t)ids[t]*DM + lane*4];
  } else {
    float4 h4 = *(const float4*)&hidden[(size_t)t*DM + lane*4];
    float4 o4 = *(const float4*)&residual[(size_t)t*DM + lane*4];
    rv.x = h4.x + o4.x; rv.y = h4.y + o4.y;
    rv.z = h4.z + o4.z; rv.w = h4.w + o4.w;
  }
  *(float4*)&residual[(size_t)t*DM + lane*4] = rv;
  float s = rv.x + rv.y + rv.z + rv.w;
  #pragma unroll
  for (int o = 32; o; o >>= 1) s += __shfl_xor(s, o);
  float mean = s * (1.0f/DM);
  float d0 = rv.x - mean, d1 = rv.y - mean, d2 = rv.z - mean, d3 = rv.w - mean;
  float q = d0*d0 + d1*d1 + d2*d2 + d3*d3;
  #pragma unroll
  for (int o = 32; o; o >>= 1) q += __shfl_xor(q, o);
  float rsig = rsqrtf(q * (1.0f/DM) + EPSF);
  float4 w4 = *(const float4*)&w[lane*4];
  float4 b4 = *(const float4*)&bia[lane*4];
  float v0 = d0*rsig*w4.x + b4.x;
  float v1 = d1*rsig*w4.y + b4.y;
  float v2 = d2*rsig*w4.z + b4.z;
  float v3 = d3*rsig*w4.w + b4.w;
  if (write32) {
    float4 o4; o4.x = v0; o4.y = v1; o4.z = v2; o4.w = v3;
    *(float4*)&out[(size_t)t*DM + lane*4] = o4;
  }
  bf16x4 bv;
  bv[0] = (__bf16)v0; bv[1] = (__bf16)v1; bv[2] = (__bf16)v2; bv[3] = (__bf16)v3;
  *(bf16x4*)&out_bf[(size_t)t*DM + lane*4] = bv;
}

// ---------------- bf16 MFMA GEMM (in_proj): tile M=64, E=128 ----------------
// cols<512 -> xm bf16; cols>=512 -> zg = silu(z) bf16.  (R5-verified)
__global__ __launch_bounds__(256, 2) void gemm_in_bf16(const __bf16* __restrict__ A,
                                                       const __bf16* __restrict__ W,
                                                       __bf16* __restrict__ xm,
                                                       __bf16* __restrict__ zg) {
  __shared__ __bf16 As[4*64*8];
  __shared__ __bf16 Ws[8*64*8];
  const int K = DM;
  int tid = threadIdx.x;
  int lane = tid & 63, wv = tid >> 6;
  int bm = blockIdx.y * 64, be = blockIdx.x * 128;
  int ss = tid >> 6, sq = (tid >> 4) & 3, sm = tid & 15;
  f32x4 acc[8];
  #pragma unroll
  for (int et = 0; et < 8; ++et) acc[et] = (f32x4){0.f, 0.f, 0.f, 0.f};
  for (int k0 = 0; k0 < K; k0 += 32) {
    bf16x8 av = *(const bf16x8*)&A[(size_t)(bm + ss*16 + sm)*K + k0 + sq*8];
    bf16x8 w0 = *(const bf16x8*)&W[(size_t)(be + ss*16 + sm)*K + k0 + sq*8];
    bf16x8 w1 = *(const bf16x8*)&W[(size_t)(be + 64 + ss*16 + sm)*K + k0 + sq*8];
    __syncthreads();
    *(bf16x8*)&As[((ss*4 + sq)*16 + sm)*8] = av;
    *(bf16x8*)&Ws[((ss*4 + sq)*16 + sm)*8] = w0;
    *(bf16x8*)&Ws[(((4 + ss)*4 + sq)*16 + sm)*8] = w1;
    __syncthreads();
    bf16x8 af = *(const bf16x8*)&As[(wv*64 + lane)*8];
    #pragma unroll
    for (int et = 0; et < 8; ++et) {
      bf16x8 bfr = *(const bf16x8*)&Ws[(et*64 + lane)*8];
      acc[et] = __builtin_amdgcn_mfma_f32_16x16x32_bf16(af, bfr, acc[et], 0, 0, 0);
    }
  }
  int row0 = bm + wv*16 + (lane >> 4)*4;
  int colb = lane & 15;
  #pragma unroll
  for (int et = 0; et < 8; ++et) {
    int col = be + et*16 + colb;
    if (col < DI) {
      #pragma unroll
      for (int r = 0; r < 4; ++r)
        xm[(size_t)(row0 + r)*DI + col] = (__bf16)acc[et][r];
    } else {
      #pragma unroll
      for (int r = 0; r < 4; ++r) {
        float zv = acc[et][r];
        zg[(size_t)(row0 + r)*DI + col - DI] = (__bf16)(zv * sigmoid_f(zv));
      }
    }
  }
}

// ---------------- bf16 MFMA GEMM (out_proj): tile M=64, E=64, fp32 C ----------------
__global__ __launch_bounds__(256, 2) void gemm_out_bf16(const __bf16* __restrict__ A,
                                                        const __bf16* __restrict__ W,
                                                        float* __restrict__ C) {
  __shared__ __bf16 As[4*64*8];
  __shared__ __bf16 Ws[4*64*8];
  const int K = DI, E = DM;
  int tid = threadIdx.x;
  int lane = tid & 63, wv = tid >> 6;
  int bm = blockIdx.y * 64, be = blockIdx.x * 64;
  int ss = tid >> 6, sq = (tid >> 4) & 3, sm = tid & 15;
  f32x4 acc[4];
  #pragma unroll
  for (int et = 0; et < 4; ++et) acc[et] = (f32x4){0.f, 0.f, 0.f, 0.f};
  for (int k0 = 0; k0 < K; k0 += 32) {
    bf16x8 av = *(const bf16x8*)&A[(size_t)(bm + ss*16 + sm)*K + k0 + sq*8];
    bf16x8 wvv = *(const bf16x8*)&W[(size_t)(be + ss*16 + sm)*K + k0 + sq*8];
    __syncthreads();
    *(bf16x8*)&As[((ss*4 + sq)*16 + sm)*8] = av;
    *(bf16x8*)&Ws[((ss*4 + sq)*16 + sm)*8] = wvv;
    __syncthreads();
    bf16x8 af = *(const bf16x8*)&As[(wv*64 + lane)*8];
    #pragma unroll
    for (int et = 0; et < 4; ++et) {
      bf16x8 bfr = *(const bf16x8*)&Ws[(et*64 + lane)*8];
      acc[et] = __builtin_amdgcn_mfma_f32_16x16x32_bf16(af, bfr, acc[et], 0, 0, 0);
    }
  }
  int row0 = bm + wv*16 + (lane >> 4)*4;
  int col0 = be + (lane & 15);
  #pragma unroll
  for (int et = 0; et < 4; ++et)
    #pragma unroll
    for (int r = 0; r < 4; ++r)
      C[(size_t)(row0 + r)*E + col0 + et*16] = acc[et][r];
}

// ------- fused x_proj + scan pass1 (R8-verified): one 16-token chunk per block -------
__global__ __launch_bounds__(512) void xproj_scan1(
    const __bf16* __restrict__ xm, const float* __restrict__ cw,
    const float* __restrict__ cb, const __bf16* __restrict__ Wbf,
    const float* __restrict__ dtw, const float* __restrict__ dtb,
    const float* __restrict__ A_log, const float* __restrict__ Dp,
    float* __restrict__ xdbl, float* __restrict__ hloc,
    float* __restrict__ dsum, float* __restrict__ ylocal,
    float* __restrict__ csout) {
  __shared__ float red[8][3][16][16];           // 24 KB
  __shared__ __bf16 xc_s[CHUNK][DI];            // 16 KB, cols XOR-swizzled
  __shared__ __align__(16) float DBC[CHUNK][48];// 3 KB  [l][dt|B|C]
  int tid = threadIdx.x;
  int lane = tid & 63, w = tid >> 6;            // 8 waves
  int bc = blockIdx.x;                          // chunk id; t0 = bc*16
  int t0 = bc * CHUNK;
  int b = bc >> 7, c = bc & (NCH - 1);
  int r16 = lane & 15;
  int row = t0 + r16;
  int l = row & (LL - 1);
  int kg = (lane >> 4) * 8;

  // ---- phase A: conv+silu + x_proj MFMA ----
  f32x4 acc[3];
  #pragma unroll
  for (int e = 0; e < 3; ++e) acc[e] = (f32x4){0.f, 0.f, 0.f, 0.f};
  #pragma unroll
  for (int ks = 0; ks < 2; ++ks) {
    int ch = w*64 + ks*32 + kg;
    bf16x8 v0 = *(const bf16x8*)&xm[(size_t)row*DI + ch];
    bf16x8 v1 = (l >= 1) ? *(const bf16x8*)&xm[(size_t)(row-1)*DI + ch] : (bf16x8)(__bf16)0;
    bf16x8 v2 = (l >= 2) ? *(const bf16x8*)&xm[(size_t)(row-2)*DI + ch] : (bf16x8)(__bf16)0;
    bf16x8 v3 = (l >= 3) ? *(const bf16x8*)&xm[(size_t)(row-3)*DI + ch] : (bf16x8)(__bf16)0;
    bf16x8 a8;
    #pragma unroll
    for (int j = 0; j < 8; ++j) {
      float4 cwv = *(const float4*)&cw[(ch + j)*KC];
      float cv = cb[ch + j];
      cv = fmaf(cwv.x, (float)v3[j], cv);
      cv = fmaf(cwv.y, (float)v2[j], cv);
      cv = fmaf(cwv.z, (float)v1[j], cv);
      cv = fmaf(cwv.w, (float)v0[j], cv);
      a8[j] = (__bf16)(cv * sigmoid_f(cv));
    }
    *(bf16x8*)&xc_s[r16][ch ^ ((r16 & 7) << 3)] = a8;   // swizzled LDS store
    #pragma unroll
    for (int e = 0; e < 3; ++e) {
      bf16x8 bv = *(const bf16x8*)&Wbf[(size_t)(e*16 + r16)*DI + ch];
      acc[e] = __builtin_amdgcn_mfma_f32_16x16x32_bf16(a8, bv, acc[e], 0, 0, 0);
    }
  }
  #pragma unroll
  for (int e = 0; e < 3; ++e)
    #pragma unroll
    for (int r = 0; r < 4; ++r)
      red[w][e][(lane >> 4)*4 + r][r16] = acc[e][r];
  __syncthreads();
  for (int idx = tid; idx < 768; idx += 512) {
    int e = idx >> 8, rr = (idx >> 4) & 15, cc = idx & 15;
    float s = 0.f;
    #pragma unroll
    for (int w8 = 0; w8 < 8; ++w8) s += red[w8][e][rr][cc];
    DBC[rr][e*16 + cc] = s;
    xdbl[(size_t)(t0 + rr)*XDIM + e*16 + cc] = s;  // pass3 reads the C rows
  }
  __syncthreads();

  // ---- phase B: serial 16-step scan, d = tid (all 512 channels) ----
  int d = tid;
  float4 wq[4];
  #pragma unroll
  for (int i = 0; i < 4; ++i) wq[i] = *(const float4*)&dtw[(size_t)d*RDT + i*4];
  float dtbv = dtb[d];
  float Dpv = Dp[d];
  float A[NST];
  #pragma unroll
  for (int n = 0; n < NST; ++n) A[n] = -__expf(A_log[d*NST + n]);
  float A0 = A[0];
  bool geo = true;
  #pragma unroll
  for (int n = 1; n < NST; ++n) {
    float ideal = A0 * (float)(n+1);
    geo = geo && (fabsf(A[n] - ideal) <= 1e-5f * fabsf(ideal));
  }
  float h[NST];
  #pragma unroll
  for (int n = 0; n < NST; ++n) h[n] = 0.f;
  float ds = 0.f;
  for (int lp = 0; lp < CHUNK; ++lp) {
    int t = t0 + lp;
    float xcv = (float)xc_s[lp][d ^ ((lp & 7) << 3)];
    float acs = dtbv;
    #pragma unroll
    for (int i = 0; i < 4; ++i) {
      float4 a = *(const float4*)&DBC[lp][i*4];
      acs = fmaf(a.x, wq[i].x, acs); acs = fmaf(a.y, wq[i].y, acs);
      acs = fmaf(a.z, wq[i].z, acs); acs = fmaf(a.w, wq[i].w, acs);
    }
    float del = fmaxf(acs, 0.f) + log1pf(__expf(-fabsf(acs)));
    ds += del;
    float dx = del * xcv;
    float yv = 0.f;
    if (geo) {
      float e = __expf(del * A0);
      float dA = e;
      h[0] = fmaf(dA, h[0], dx * DBC[lp][16]);
      yv = fmaf(h[0], DBC[lp][32], yv);
      #pragma unroll
      for (int n = 1; n < NST; ++n) {
        dA *= e;
        h[n] = fmaf(dA, h[n], dx * DBC[lp][16 + n]);
        yv = fmaf(h[n], DBC[lp][32 + n], yv);
      }
    } else {
      #pragma unroll
      for (int n = 0; n < NST; ++n) {
        h[n] = fmaf(__expf(del * A[n]), h[n], dx * DBC[lp][16 + n]);
        yv = fmaf(h[n], DBC[lp][32 + n], yv);
      }
    }
    yv = fmaf(Dpv, xcv, yv);
    ylocal[(size_t)t*DI + d] = yv;
    csout[(size_t)t*DI + d] = ds;
  }
  #pragma unroll
  for (int n = 0; n < NST; ++n)
    hloc[((size_t)(b*NST + n)*NCH + c)*DI + d] = h[n];
  dsum[(size_t)bc*DI + d] = ds;
}

// ---- pass2: segmented affine scan, 8 threads/chain (16 chunks each) ----
// Chain op: h -> P*h + hloc, P = exp(A*dsum). Each thread computes its
// segment's affine map (Pseg, Bseg); 7-step in-wave shfl compose gives the
// exclusive prefix; 16-step replay (P cached in regs) writes hinit.
// 131072 threads = 512 blocks x 256 -> 8 waves/CU (was 1 wave/CU).
__global__ __launch_bounds__(256) void scan_pass2(
    const float* __restrict__ hloc, const float* __restrict__ dsum,
    const float* __restrict__ A_log, float* __restrict__ hinit) {
  int g = blockIdx.x*256 + threadIdx.x;   // chain*8 + q
  int q = g & 7;
  int chain = g >> 3;
  int d = chain & (DI-1);
  int n = (chain >> 9) & (NST-1);
  int b = chain >> 13;
  float A = -__expf(A_log[d*NST + n]);
  size_t base  = (size_t)(b*NST + n)*NCH*DI + d;
  size_t dbase = (size_t)(b*NCH)*DI + d;
  int c0 = q*16;
  // pass 1: segment affine map (Pseg, Bseg); cache per-chunk P in regs
  float Pc[16];
  float hc = 0.f, Pp = 1.f;
  #pragma unroll
  for (int i = 0; i < 16; ++i) {
    int cc = c0 + i;
    float P = __expf(A * dsum[dbase + (size_t)cc*DI]);
    Pc[i] = P;
    hc = fmaf(P, hc, hloc[base + (size_t)cc*DI]);
    Pp *= P;
  }
  float Pseg = Pp, Bseg = hc;
  // exclusive compose across the 8 segment-threads of this chain (in-wave)
  int lane = threadIdx.x & 63;
  int lb = lane & ~7;
  float hin = 0.f;
  #pragma unroll
  for (int j = 0; j < 7; ++j) {
    float Pj = __shfl(Pseg, lb + j);
    float Bj = __shfl(Bseg, lb + j);
    if (j < q) hin = fmaf(Pj, hin, Bj);
  }
  // pass 2: replay segment writing hinit
  hc = hin;
  #pragma unroll
  for (int i = 0; i < 16; ++i) {
    int cc = c0 + i;
    hinit[base + (size_t)cc*DI] = hc;
    hc = fmaf(Pc[i], hc, hloc[base + (size_t)cc*DI]);
  }
}

// pass3: fully parallel correction + gate.  y = (ylocal + sum_n C*G*hinit)*zg.
__global__ __launch_bounds__(256) void scan_pass3(
    const float* __restrict__ cs, const float* __restrict__ ylocal,
    const __bf16* __restrict__ zg, const float* __restrict__ xdbl,
    const float* __restrict__ A_log, const float* __restrict__ hinit,
    __bf16* __restrict__ y) {
  __shared__ __align__(16) float Cs[CHUNK][16];
  int bc = blockIdx.x >> 1;
  int d  = ((blockIdx.x & 1) << 8) + threadIdx.x;
  int b = bc >> 7, c = bc & (NCH-1);
  int t0 = b*LL + c*CHUNK;
  int tid = threadIdx.x;
  if (tid < CHUNK*4) {
    int row = tid >> 2, q = tid & 3;
    *(float4*)&Cs[row][q*4] = *(const float4*)&xdbl[(size_t)(t0+row)*XDIM + 32 + q*4];
  }
  __syncthreads();
  float A[NST];
  #pragma unroll
  for (int n = 0; n < NST; ++n) A[n] = -__expf(A_log[d*NST + n]);
  float A0 = A[0];
  bool geo = true;
  #pragma unroll
  for (int n = 1; n < NST; ++n) {
    float ideal = A0 * (float)(n+1);
    geo = geo && (fabsf(A[n] - ideal) <= 1e-5f * fabsf(ideal));
  }
  float hin[NST];
  #pragma unroll
  for (int n = 0; n < NST; ++n) hin[n] = hinit[((size_t)(b*NST + n)*NCH + c)*DI + d];
  for (int l = 0; l < CHUNK; ++l) {
    int t = t0 + l;
    float csv = cs[(size_t)t*DI + d];
    float ylv = ylocal[(size_t)t*DI + d];
    float zvg = (float)zg[(size_t)t*DI + d];
    float corr = 0.f;
    if (geo) {
      float g = __expf(csv * A0);
      float dA = g;
      corr = hin[0] * dA * Cs[l][0];
      #pragma unroll
      for (int n = 1; n < NST; ++n) {
        dA *= g;
        corr = fmaf(hin[n] * dA, Cs[l][n], corr);
      }
    } else {
      #pragma unroll
      for (int n = 0; n < NST; ++n)
        corr = fmaf(hin[n] * __expf(A[n] * csv), Cs[l][n], corr);
    }
    y[(size_t)t*DI + d] = (__bf16)((ylv + corr) * zvg);
  }
}

// ---------------- pool stage 1: partial sums over L (256 blocks) ----------------
__global__ void pool1_kernel(const float* __restrict__ ln, float* __restrict__ part) {
  int blk = blockIdx.x;             // b*128 + c
  int b = blk >> 7, c = blk & 127;
  int d = threadIdx.x;
  const float* base = ln + (size_t)b*LL*DM + (size_t)c*16*DM + d;
  float s = 0.f;
  #pragma unroll
  for (int l = 0; l < 16; ++l) s += base[(size_t)l*DM];
  part[(size_t)blk*DM + d] = s;
}

// ---------------- pool stage 2 + decode ----------------
__global__ void pool_decode_kernel(const float* __restrict__ part, const float* __restrict__ dw,
                                   const float* __restrict__ db, float* __restrict__ out) {
  int b = blockIdx.x, d = threadIdx.x;
  __shared__ float pooled[DM];
  float s = 0.f;
  for (int c = 0; c < 128; ++c) s += part[(size_t)(b*128 + c)*DM + d];
  pooled[d] = s * (1.0f/LL);
  __syncthreads();
  if (d < DOUT) {
    float acc = db[d];
    for (int m = 0; m < DM; ++m) acc = fmaf(pooled[m], dw[d*DM + m], acc);
    out[b*DOUT + d] = acc;
  }
}

extern "C" void kernel_launch(void* const* d_in, const int* in_sizes, int n_in,
                              void* d_out, int out_size, void* d_ws, size_t ws_size,
                              hipStream_t stream) {
  const int*   ids     = (const int*)d_in[0];
  const float* emb     = (const float*)d_in[1];
  const float* norm_w  = (const float*)d_in[2];
  const float* norm_b  = (const float*)d_in[3];
  const float* in_w    = (const float*)d_in[4];
  const float* conv_w  = (const float*)d_in[5];
  const float* conv_b  = (const float*)d_in[6];
  const float* xp_w    = (const float*)d_in[7];
  const float* dt_w    = (const float*)d_in[8];
  const float* dt_b    = (const float*)d_in[9];
  const float* A_log   = (const float*)d_in[10];
  const float* Dp      = (const float*)d_in[11];
  const float* out_w   = (const float*)d_in[12];
  const float* normf_w = (const float*)d_in[13];
  const float* normf_b = (const float*)d_in[14];
  const float* dec_w   = (const float*)d_in[15];
  const float* dec_b   = (const float*)d_in[16];
  float* out = (float*)d_out;

  float* ws = (float*)d_ws;
  float* hidden   = ws; ws += TOK*DM;
  float* residual = ws; ws += TOK*DM;
  float* hbuf     = ws; ws += TOK*DM;
  float* xdblbuf  = ws; ws += TOK*XDIM;
  float* hlocbuf  = ws; ws += (size_t)BB*NCH*NST*DI;
  float* hinitbuf = ws; ws += (size_t)BB*NCH*NST*DI;
  float* dsumbuf  = ws; ws += (size_t)BB*NCH*DI;
  float* partbuf  = ws; ws += (size_t)BB*128*DM;
  float* csbuf    = ws; ws += (size_t)TOK*DI;
  float* ylbuf    = ws; ws += (size_t)TOK*DI;
  __bf16* xmbuf   = (__bf16*)ws; ws += TOK*DI/2;
  __bf16* zgbuf   = (__bf16*)ws; ws += TOK*DI/2;
  __bf16* hbuf_bf = (__bf16*)ws; ws += TOK*DM/2;
  __bf16* ybuf_bf = (__bf16*)ws; ws += TOK*DI/2;
  __bf16* inw_bf  = (__bf16*)ws; ws += (size_t)NLAY*2*DI*DM/2;
  __bf16* outw_bf = (__bf16*)ws; ws += (size_t)NLAY*DM*DI/2;
  __bf16* xpw_bf  = (__bf16*)ws; ws += (size_t)NLAY*XDIM*DI/2 + 256;

  const int n_inw = NLAY*2*DI*DM, n_outw = NLAY*DM*DI, n_xpw = NLAY*XDIM*DI;
  cast_w_kernel<<<2048, 256, 0, stream>>>(in_w, out_w, xp_w, inw_bf, outw_bf, xpw_bf,
                                          n_inw, n_outw, n_xpw);

  for (int i = 0; i < NLAY; ++i) {
    add_ln_kernel<<<TOK/4, 256, 0, stream>>>(residual, hidden, ids, emb,
                                             norm_w + i*DM, norm_b + i*DM,
                                             hbuf, hbuf_bf, i == 0, 0);
    gemm_in_bf16<<<dim3((2*DI)/128, TOK/64), 256, 0, stream>>>(
        hbuf_bf, inw_bf + (size_t)i*2*DI*DM, xmbuf, zgbuf);
    xproj_scan1<<<TOK/CHUNK, 512, 0, stream>>>(
        xmbuf, conv_w + i*DI*KC, conv_b + i*DI,
        xpw_bf + (size_t)i*XDIM*DI,
        dt_w + (size_t)i*DI*RDT, dt_b + i*DI, A_log + (size_t)i*DI*NST,
        Dp + i*DI, xdblbuf, hlocbuf, dsumbuf, ylbuf, csbuf);
    scan_pass2<<<(BB*NST*DI*8)/256, 256, 0, stream>>>(
        hlocbuf, dsumbuf, A_log + (size_t)i*DI*NST, hinitbuf);
    scan_pass3<<<BB*NCH*(DI/256), 256, 0, stream>>>(
        csbuf, ylbuf, zgbuf, xdblbuf, A_log + (size_t)i*DI*NST,
        hinitbuf, ybuf_bf);
    gemm_out_bf16<<<dim3(DM/64, TOK/64), 256, 0, stream>>>(
        ybuf_bf, outw_bf + (size_t)i*DM*DI, hidden);
  }

  add_ln_kernel<<<TOK/4, 256, 0, stream>>>(residual, hidden, ids, emb,
                                           normf_w, normf_b, hbuf, hbuf_bf, 0, 1);
  pool1_kernel<<<BB*128, DM, 0, stream>>>(hbuf, partbuf);
  pool_decode_kernel<<<BB, DM, 0, stream>>>(partbuf, dec_w, dec_b, out);
}

// Round 10
// 363.016 us; speedup vs baseline: 1.3279x; 1.0204x over previous
//
#include <hip/hip_runtime.h>
#include <hip/hip_bf16.h>

#define BB 2
#define LL 2048
#define DM 256
#define DI 512
#define NST 16
#define RDT 16
#define KC 4
#define NLAY 4
#define DOUT 10
#define XDIM 48            // R + 2N
#define TOK (BB*LL)        // 4096
#define EPSF 1e-5f
#define CHUNK 16
#define NCH (LL/CHUNK)     // 128

typedef __bf16 bf16x8 __attribute__((ext_vector_type(8)));
typedef __bf16 bf16x4 __attribute__((ext_vector_type(4)));
typedef float  f32x4  __attribute__((ext_vector_type(4)));

__device__ __forceinline__ float sigmoid_f(float x) { return 1.0f / (1.0f + __expf(-x)); }

// ---------------- weight cast fp32 -> bf16 (once per call) ----------------
__global__ void cast_w_kernel(const float* __restrict__ a, const float* __restrict__ b,
                              const float* __restrict__ c,
                              __bf16* __restrict__ ab, __bf16* __restrict__ bb,
                              __bf16* __restrict__ cbf,
                              int na, int nb, int nc) {
  int stride = gridDim.x * 256;
  for (int i = blockIdx.x*256 + threadIdx.x; i < na; i += stride) ab[i] = (__bf16)a[i];
  for (int i = blockIdx.x*256 + threadIdx.x; i < nb; i += stride) bb[i] = (__bf16)b[i];
  for (int i = blockIdx.x*256 + threadIdx.x; i < nc; i += stride) cbf[i] = (__bf16)c[i];
}

// ------- residual add + layernorm, wave-per-token: no barriers, no LDS -------
// 4 tokens/block (4 waves x 64 lanes x float4). Grid = TOK/4.  (R9-verified)
__global__ void add_ln_kernel(float* __restrict__ residual, const float* __restrict__ hidden,
                              const int* __restrict__ ids, const float* __restrict__ emb,
                              const float* __restrict__ w, const float* __restrict__ bia,
                              float* __restrict__ out, __bf16* __restrict__ out_bf,
                              int first, int write32) {
  int wv = threadIdx.x >> 6, lane = threadIdx.x & 63;
  int t = blockIdx.x*4 + wv;
  float4 rv;
  if (first) {
    rv = *(const float4*)&emb[(size_t)ids[t]*DM + lane*4];
  } else {
    float4 h4 = *(const float4*)&hidden[(size_t)t*DM + lane*4];
    float4 o4 = *(const float4*)&residual[(size_t)t*DM + lane*4];
    rv.x = h4.x + o4.x; rv.y = h4.y + o4.y;
    rv.z = h4.z + o4.z; rv.w = h4.w + o4.w;
  }
  *(float4*)&residual[(size_t)t*DM + lane*4] = rv;
  float s = rv.x + rv.y + rv.z + rv.w;
  #pragma unroll
  for (int o = 32; o; o >>= 1) s += __shfl_xor(s, o);
  float mean = s * (1.0f/DM);
  float d0 = rv.x - mean, d1 = rv.y - mean, d2 = rv.z - mean, d3 = rv.w - mean;
  float q = d0*d0 + d1*d1 + d2*d2 + d3*d3;
  #pragma unroll
  for (int o = 32; o; o >>= 1) q += __shfl_xor(q, o);
  float rsig = rsqrtf(q * (1.0f/DM) + EPSF);
  float4 w4 = *(const float4*)&w[lane*4];
  float4 b4 = *(const float4*)&bia[lane*4];
  float v0 = d0*rsig*w4.x + b4.x;
  float v1 = d1*rsig*w4.y + b4.y;
  float v2 = d2*rsig*w4.z + b4.z;
  float v3 = d3*rsig*w4.w + b4.w;
  if (write32) {
    float4 o4; o4.x = v0; o4.y = v1; o4.z = v2; o4.w = v3;
    *(float4*)&out[(size_t)t*DM + lane*4] = o4;
  }
  bf16x4 bv;
  bv[0] = (__bf16)v0; bv[1] = (__bf16)v1; bv[2] = (__bf16)v2; bv[3] = (__bf16)v3;
  *(bf16x4*)&out_bf[(size_t)t*DM + lane*4] = bv;
}

// ---------------- bf16 MFMA GEMM (in_proj): tile M=64, E=128 ----------------
// Double-buffered A+W: 1 barrier per k-step (8 vs 16). Writes to buf[(k+1)&1]
// never race reads of buf[k&1]; next iteration's barrier publishes them.
__global__ __launch_bounds__(256, 2) void gemm_in_bf16(const __bf16* __restrict__ A,
                                                       const __bf16* __restrict__ W,
                                                       __bf16* __restrict__ xm,
                                                       __bf16* __restrict__ zg) {
  __shared__ __bf16 As[2][4*64*8];   // 8 KB
  __shared__ __bf16 Ws[2][8*64*8];   // 16 KB
  const int K = DM;
  int tid = threadIdx.x;
  int lane = tid & 63, wv = tid >> 6;
  int bm = blockIdx.y * 64, be = blockIdx.x * 128;
  int ss = tid >> 6, sq = (tid >> 4) & 3, sm = tid & 15;
  f32x4 acc[8];
  #pragma unroll
  for (int et = 0; et < 8; ++et) acc[et] = (f32x4){0.f, 0.f, 0.f, 0.f};
  // prologue: stage k=0 tile
  {
    bf16x8 av = *(const bf16x8*)&A[(size_t)(bm + ss*16 + sm)*K + sq*8];
    bf16x8 w0 = *(const bf16x8*)&W[(size_t)(be + ss*16 + sm)*K + sq*8];
    bf16x8 w1 = *(const bf16x8*)&W[(size_t)(be + 64 + ss*16 + sm)*K + sq*8];
    *(bf16x8*)&As[0][((ss*4 + sq)*16 + sm)*8] = av;
    *(bf16x8*)&Ws[0][((ss*4 + sq)*16 + sm)*8] = w0;
    *(bf16x8*)&Ws[0][(((4 + ss)*4 + sq)*16 + sm)*8] = w1;
  }
  for (int k = 0; k < 8; ++k) {
    int k0 = k*32;
    bf16x8 na, nw0, nw1;
    if (k < 7) {
      na  = *(const bf16x8*)&A[(size_t)(bm + ss*16 + sm)*K + k0 + 32 + sq*8];
      nw0 = *(const bf16x8*)&W[(size_t)(be + ss*16 + sm)*K + k0 + 32 + sq*8];
      nw1 = *(const bf16x8*)&W[(size_t)(be + 64 + ss*16 + sm)*K + k0 + 32 + sq*8];
    }
    __syncthreads();
    bf16x8 af = *(const bf16x8*)&As[k & 1][(wv*64 + lane)*8];
    #pragma unroll
    for (int et = 0; et < 8; ++et) {
      bf16x8 bfr = *(const bf16x8*)&Ws[k & 1][(et*64 + lane)*8];
      acc[et] = __builtin_amdgcn_mfma_f32_16x16x32_bf16(af, bfr, acc[et], 0, 0, 0);
    }
    if (k < 7) {
      *(bf16x8*)&As[(k+1) & 1][((ss*4 + sq)*16 + sm)*8] = na;
      *(bf16x8*)&Ws[(k+1) & 1][((ss*4 + sq)*16 + sm)*8] = nw0;
      *(bf16x8*)&Ws[(k+1) & 1][(((4 + ss)*4 + sq)*16 + sm)*8] = nw1;
    }
  }
  int row0 = bm + wv*16 + (lane >> 4)*4;
  int colb = lane & 15;
  #pragma unroll
  for (int et = 0; et < 8; ++et) {
    int col = be + et*16 + colb;
    if (col < DI) {
      #pragma unroll
      for (int r = 0; r < 4; ++r)
        xm[(size_t)(row0 + r)*DI + col] = (__bf16)acc[et][r];
    } else {
      #pragma unroll
      for (int r = 0; r < 4; ++r) {
        float zv = acc[et][r];
        zg[(size_t)(row0 + r)*DI + col - DI] = (__bf16)(zv * sigmoid_f(zv));
      }
    }
  }
}

// ---------------- bf16 MFMA GEMM (out_proj): tile M=64, E=64, fp32 C ----------------
// Double-buffered A+W: 1 barrier per k-step (16 vs 32).
__global__ __launch_bounds__(256, 2) void gemm_out_bf16(const __bf16* __restrict__ A,
                                                        const __bf16* __restrict__ W,
                                                        float* __restrict__ C) {
  __shared__ __bf16 As[2][4*64*8];
  __shared__ __bf16 Ws[2][4*64*8];
  const int K = DI, E = DM;
  int tid = threadIdx.x;
  int lane = tid & 63, wv = tid >> 6;
  int bm = blockIdx.y * 64, be = blockIdx.x * 64;
  int ss = tid >> 6, sq = (tid >> 4) & 3, sm = tid & 15;
  f32x4 acc[4];
  #pragma unroll
  for (int et = 0; et < 4; ++et) acc[et] = (f32x4){0.f, 0.f, 0.f, 0.f};
  {
    bf16x8 av  = *(const bf16x8*)&A[(size_t)(bm + ss*16 + sm)*K + sq*8];
    bf16x8 wvv = *(const bf16x8*)&W[(size_t)(be + ss*16 + sm)*K + sq*8];
    *(bf16x8*)&As[0][((ss*4 + sq)*16 + sm)*8] = av;
    *(bf16x8*)&Ws[0][((ss*4 + sq)*16 + sm)*8] = wvv;
  }
  for (int k = 0; k < 16; ++k) {
    int k0 = k*32;
    bf16x8 na, nw;
    if (k < 15) {
      na = *(const bf16x8*)&A[(size_t)(bm + ss*16 + sm)*K + k0 + 32 + sq*8];
      nw = *(const bf16x8*)&W[(size_t)(be + ss*16 + sm)*K + k0 + 32 + sq*8];
    }
    __syncthreads();
    bf16x8 af = *(const bf16x8*)&As[k & 1][(wv*64 + lane)*8];
    #pragma unroll
    for (int et = 0; et < 4; ++et) {
      bf16x8 bfr = *(const bf16x8*)&Ws[k & 1][(et*64 + lane)*8];
      acc[et] = __builtin_amdgcn_mfma_f32_16x16x32_bf16(af, bfr, acc[et], 0, 0, 0);
    }
    if (k < 15) {
      *(bf16x8*)&As[(k+1) & 1][((ss*4 + sq)*16 + sm)*8] = na;
      *(bf16x8*)&Ws[(k+1) & 1][((ss*4 + sq)*16 + sm)*8] = nw;
    }
  }
  int row0 = bm + wv*16 + (lane >> 4)*4;
  int col0 = be + (lane & 15);
  #pragma unroll
  for (int et = 0; et < 4; ++et)
    #pragma unroll
    for (int r = 0; r < 4; ++r)
      C[(size_t)(row0 + r)*E + col0 + et*16] = acc[et][r];
}

// ------- fused x_proj + scan pass1 (R8-verified): one 16-token chunk per block -------
// xdbl global write trimmed to the C rows (cols 32..47) — only pass3 reads it.
__global__ __launch_bounds__(512) void xproj_scan1(
    const __bf16* __restrict__ xm, const float* __restrict__ cw,
    const float* __restrict__ cb, const __bf16* __restrict__ Wbf,
    const float* __restrict__ dtw, const float* __restrict__ dtb,
    const float* __restrict__ A_log, const float* __restrict__ Dp,
    float* __restrict__ xdbl, float* __restrict__ hloc,
    float* __restrict__ dsum, float* __restrict__ ylocal,
    float* __restrict__ csout) {
  __shared__ float red[8][3][16][16];           // 24 KB
  __shared__ __bf16 xc_s[CHUNK][DI];            // 16 KB, cols XOR-swizzled
  __shared__ __align__(16) float DBC[CHUNK][48];// 3 KB  [l][dt|B|C]
  int tid = threadIdx.x;
  int lane = tid & 63, w = tid >> 6;            // 8 waves
  int bc = blockIdx.x;                          // chunk id; t0 = bc*16
  int t0 = bc * CHUNK;
  int b = bc >> 7, c = bc & (NCH - 1);
  int r16 = lane & 15;
  int row = t0 + r16;
  int l = row & (LL - 1);
  int kg = (lane >> 4) * 8;

  // ---- phase A: conv+silu + x_proj MFMA ----
  f32x4 acc[3];
  #pragma unroll
  for (int e = 0; e < 3; ++e) acc[e] = (f32x4){0.f, 0.f, 0.f, 0.f};
  #pragma unroll
  for (int ks = 0; ks < 2; ++ks) {
    int ch = w*64 + ks*32 + kg;
    bf16x8 v0 = *(const bf16x8*)&xm[(size_t)row*DI + ch];
    bf16x8 v1 = (l >= 1) ? *(const bf16x8*)&xm[(size_t)(row-1)*DI + ch] : (bf16x8)(__bf16)0;
    bf16x8 v2 = (l >= 2) ? *(const bf16x8*)&xm[(size_t)(row-2)*DI + ch] : (bf16x8)(__bf16)0;
    bf16x8 v3 = (l >= 3) ? *(const bf16x8*)&xm[(size_t)(row-3)*DI + ch] : (bf16x8)(__bf16)0;
    bf16x8 a8;
    #pragma unroll
    for (int j = 0; j < 8; ++j) {
      float4 cwv = *(const float4*)&cw[(ch + j)*KC];
      float cv = cb[ch + j];
      cv = fmaf(cwv.x, (float)v3[j], cv);
      cv = fmaf(cwv.y, (float)v2[j], cv);
      cv = fmaf(cwv.z, (float)v1[j], cv);
      cv = fmaf(cwv.w, (float)v0[j], cv);
      a8[j] = (__bf16)(cv * sigmoid_f(cv));
    }
    *(bf16x8*)&xc_s[r16][ch ^ ((r16 & 7) << 3)] = a8;   // swizzled LDS store
    #pragma unroll
    for (int e = 0; e < 3; ++e) {
      bf16x8 bv = *(const bf16x8*)&Wbf[(size_t)(e*16 + r16)*DI + ch];
      acc[e] = __builtin_amdgcn_mfma_f32_16x16x32_bf16(a8, bv, acc[e], 0, 0, 0);
    }
  }
  #pragma unroll
  for (int e = 0; e < 3; ++e)
    #pragma unroll
    for (int r = 0; r < 4; ++r)
      red[w][e][(lane >> 4)*4 + r][r16] = acc[e][r];
  __syncthreads();
  for (int idx = tid; idx < 768; idx += 512) {
    int e = idx >> 8, rr = (idx >> 4) & 15, cc = idx & 15;
    float s = 0.f;
    #pragma unroll
    for (int w8 = 0; w8 < 8; ++w8) s += red[w8][e][rr][cc];
    DBC[rr][e*16 + cc] = s;
    if (e == 2) xdbl[(size_t)(t0 + rr)*XDIM + 32 + cc] = s;  // C rows for pass3
  }
  __syncthreads();

  // ---- phase B: serial 16-step scan, d = tid (all 512 channels) ----
  int d = tid;
  float4 wq[4];
  #pragma unroll
  for (int i = 0; i < 4; ++i) wq[i] = *(const float4*)&dtw[(size_t)d*RDT + i*4];
  float dtbv = dtb[d];
  float Dpv = Dp[d];
  float A[NST];
  #pragma unroll
  for (int n = 0; n < NST; ++n) A[n] = -__expf(A_log[d*NST + n]);
  float A0 = A[0];
  bool geo = true;
  #pragma unroll
  for (int n = 1; n < NST; ++n) {
    float ideal = A0 * (float)(n+1);
    geo = geo && (fabsf(A[n] - ideal) <= 1e-5f * fabsf(ideal));
  }
  float h[NST];
  #pragma unroll
  for (int n = 0; n < NST; ++n) h[n] = 0.f;
  float ds = 0.f;
  for (int lp = 0; lp < CHUNK; ++lp) {
    int t = t0 + lp;
    float xcv = (float)xc_s[lp][d ^ ((lp & 7) << 3)];
    float acs = dtbv;
    #pragma unroll
    for (int i = 0; i < 4; ++i) {
      float4 a = *(const float4*)&DBC[lp][i*4];
      acs = fmaf(a.x, wq[i].x, acs); acs = fmaf(a.y, wq[i].y, acs);
      acs = fmaf(a.z, wq[i].z, acs); acs = fmaf(a.w, wq[i].w, acs);
    }
    float del = fmaxf(acs, 0.f) + log1pf(__expf(-fabsf(acs)));
    ds += del;
    float dx = del * xcv;
    float yv = 0.f;
    if (geo) {
      float e = __expf(del * A0);
      float dA = e;
      h[0] = fmaf(dA, h[0], dx * DBC[lp][16]);
      yv = fmaf(h[0], DBC[lp][32], yv);
      #pragma unroll
      for (int n = 1; n < NST; ++n) {
        dA *= e;
        h[n] = fmaf(dA, h[n], dx * DBC[lp][16 + n]);
        yv = fmaf(h[n], DBC[lp][32 + n], yv);
      }
    } else {
      #pragma unroll
      for (int n = 0; n < NST; ++n) {
        h[n] = fmaf(__expf(del * A[n]), h[n], dx * DBC[lp][16 + n]);
        yv = fmaf(h[n], DBC[lp][32 + n], yv);
      }
    }
    yv = fmaf(Dpv, xcv, yv);
    ylocal[(size_t)t*DI + d] = yv;
    csout[(size_t)t*DI + d] = ds;
  }
  #pragma unroll
  for (int n = 0; n < NST; ++n)
    hloc[((size_t)(b*NST + n)*NCH + c)*DI + d] = h[n];
  dsum[(size_t)bc*DI + d] = ds;
}

// ---- pass2: segmented affine scan, 8 threads/chain (R9-verified) ----
__global__ __launch_bounds__(256) void scan_pass2(
    const float* __restrict__ hloc, const float* __restrict__ dsum,
    const float* __restrict__ A_log, float* __restrict__ hinit) {
  int g = blockIdx.x*256 + threadIdx.x;   // chain*8 + q
  int q = g & 7;
  int chain = g >> 3;
  int d = chain & (DI-1);
  int n = (chain >> 9) & (NST-1);
  int b = chain >> 13;
  float A = -__expf(A_log[d*NST + n]);
  size_t base  = (size_t)(b*NST + n)*NCH*DI + d;
  size_t dbase = (size_t)(b*NCH)*DI + d;
  int c0 = q*16;
  float Pc[16];
  float hc = 0.f, Pp = 1.f;
  #pragma unroll
  for (int i = 0; i < 16; ++i) {
    int cc = c0 + i;
    float P = __expf(A * dsum[dbase + (size_t)cc*DI]);
    Pc[i] = P;
    hc = fmaf(P, hc, hloc[base + (size_t)cc*DI]);
    Pp *= P;
  }
  float Pseg = Pp, Bseg = hc;
  int lane = threadIdx.x & 63;
  int lb = lane & ~7;
  float hin = 0.f;
  #pragma unroll
  for (int j = 0; j < 7; ++j) {
    float Pj = __shfl(Pseg, lb + j);
    float Bj = __shfl(Bseg, lb + j);
    if (j < q) hin = fmaf(Pj, hin, Bj);
  }
  hc = hin;
  #pragma unroll
  for (int i = 0; i < 16; ++i) {
    int cc = c0 + i;
    hinit[base + (size_t)cc*DI] = hc;
    hc = fmaf(Pc[i], hc, hloc[base + (size_t)cc*DI]);
  }
}

// pass3: fully parallel correction + gate.  y = (ylocal + sum_n C*G*hinit)*zg.
__global__ __launch_bounds__(256) void scan_pass3(
    const float* __restrict__ cs, const float* __restrict__ ylocal,
    const __bf16* __restrict__ zg, const float* __restrict__ xdbl,
    const float* __restrict__ A_log, const float* __restrict__ hinit,
    __bf16* __restrict__ y) {
  __shared__ __align__(16) float Cs[CHUNK][16];
  int bc = blockIdx.x >> 1;
  int d  = ((blockIdx.x & 1) << 8) + threadIdx.x;
  int b = bc >> 7, c = bc & (NCH-1);
  int t0 = b*LL + c*CHUNK;
  int tid = threadIdx.x;
  if (tid < CHUNK*4) {
    int row = tid >> 2, q = tid & 3;
    *(float4*)&Cs[row][q*4] = *(const float4*)&xdbl[(size_t)(t0+row)*XDIM + 32 + q*4];
  }
  __syncthreads();
  float A[NST];
  #pragma unroll
  for (int n = 0; n < NST; ++n) A[n] = -__expf(A_log[d*NST + n]);
  float A0 = A[0];
  bool geo = true;
  #pragma unroll
  for (int n = 1; n < NST; ++n) {
    float ideal = A0 * (float)(n+1);
    geo = geo && (fabsf(A[n] - ideal) <= 1e-5f * fabsf(ideal));
  }
  float hin[NST];
  #pragma unroll
  for (int n = 0; n < NST; ++n) hin[n] = hinit[((size_t)(b*NST + n)*NCH + c)*DI + d];
  for (int l = 0; l < CHUNK; ++l) {
    int t = t0 + l;
    float csv = cs[(size_t)t*DI + d];
    float ylv = ylocal[(size_t)t*DI + d];
    float zvg = (float)zg[(size_t)t*DI + d];
    float corr = 0.f;
    if (geo) {
      float g = __expf(csv * A0);
      float dA = g;
      corr = hin[0] * dA * Cs[l][0];
      #pragma unroll
      for (int n = 1; n < NST; ++n) {
        dA *= g;
        corr = fmaf(hin[n] * dA, Cs[l][n], corr);
      }
    } else {
      #pragma unroll
      for (int n = 0; n < NST; ++n)
        corr = fmaf(hin[n] * __expf(A[n] * csv), Cs[l][n], corr);
    }
    y[(size_t)t*DI + d] = (__bf16)((ylv + corr) * zvg);
  }
}

// ---------------- pool stage 1: partial sums over L (256 blocks) ----------------
__global__ void pool1_kernel(const float* __restrict__ ln, float* __restrict__ part) {
  int blk = blockIdx.x;             // b*128 + c
  int b = blk >> 7, c = blk & 127;
  int d = threadIdx.x;
  const float* base = ln + (size_t)b*LL*DM + (size_t)c*16*DM + d;
  float s = 0.f;
  #pragma unroll
  for (int l = 0; l < 16; ++l) s += base[(size_t)l*DM];
  part[(size_t)blk*DM + d] = s;
}

// ---------------- pool stage 2 + decode ----------------
__global__ void pool_decode_kernel(const float* __restrict__ part, const float* __restrict__ dw,
                                   const float* __restrict__ db, float* __restrict__ out) {
  int b = blockIdx.x, d = threadIdx.x;
  __shared__ float pooled[DM];
  float s = 0.f;
  for (int c = 0; c < 128; ++c) s += part[(size_t)(b*128 + c)*DM + d];
  pooled[d] = s * (1.0f/LL);
  __syncthreads();
  if (d < DOUT) {
    float acc = db[d];
    for (int m = 0; m < DM; ++m) acc = fmaf(pooled[m], dw[d*DM + m], acc);
    out[b*DOUT + d] = acc;
  }
}

extern "C" void kernel_launch(void* const* d_in, const int* in_sizes, int n_in,
                              void* d_out, int out_size, void* d_ws, size_t ws_size,
                              hipStream_t stream) {
  const int*   ids     = (const int*)d_in[0];
  const float* emb     = (const float*)d_in[1];
  const float* norm_w  = (const float*)d_in[2];
  const float* norm_b  = (const float*)d_in[3];
  const float* in_w    = (const float*)d_in[4];
  const float* conv_w  = (const float*)d_in[5];
  const float* conv_b  = (const float*)d_in[6];
  const float* xp_w    = (const float*)d_in[7];
  const float* dt_w    = (const float*)d_in[8];
  const float* dt_b    = (const float*)d_in[9];
  const float* A_log   = (const float*)d_in[10];
  const float* Dp      = (const float*)d_in[11];
  const float* out_w   = (const float*)d_in[12];
  const float* normf_w = (const float*)d_in[13];
  const float* normf_b = (const float*)d_in[14];
  const float* dec_w   = (const float*)d_in[15];
  const float* dec_b   = (const float*)d_in[16];
  float* out = (float*)d_out;

  float* ws = (float*)d_ws;
  float* hidden   = ws; ws += TOK*DM;
  float* residual = ws; ws += TOK*DM;
  float* hbuf     = ws; ws += TOK*DM;
  float* xdblbuf  = ws; ws += TOK*XDIM;
  float* hlocbuf  = ws; ws += (size_t)BB*NCH*NST*DI;
  float* hinitbuf = ws; ws += (size_t)BB*NCH*NST*DI;
  float* dsumbuf  = ws; ws += (size_t)BB*NCH*DI;
  float* partbuf  = ws; ws += (size_t)BB*128*DM;
  float* csbuf    = ws; ws += (size_t)TOK*DI;
  float* ylbuf    = ws; ws += (size_t)TOK*DI;
  __bf16* xmbuf   = (__bf16*)ws; ws += TOK*DI/2;
  __bf16* zgbuf   = (__bf16*)ws; ws += TOK*DI/2;
  __bf16* hbuf_bf = (__bf16*)ws; ws += TOK*DM/2;
  __bf16* ybuf_bf = (__bf16*)ws; ws += TOK*DI/2;
  __bf16* inw_bf  = (__bf16*)ws; ws += (size_t)NLAY*2*DI*DM/2;
  __bf16* outw_bf = (__bf16*)ws; ws += (size_t)NLAY*DM*DI/2;
  __bf16* xpw_bf  = (__bf16*)ws; ws += (size_t)NLAY*XDIM*DI/2 + 256;

  const int n_inw = NLAY*2*DI*DM, n_outw = NLAY*DM*DI, n_xpw = NLAY*XDIM*DI;
  cast_w_kernel<<<2048, 256, 0, stream>>>(in_w, out_w, xp_w, inw_bf, outw_bf, xpw_bf,
                                          n_inw, n_outw, n_xpw);

  for (int i = 0; i < NLAY; ++i) {
    add_ln_kernel<<<TOK/4, 256, 0, stream>>>(residual, hidden, ids, emb,
                                             norm_w + i*DM, norm_b + i*DM,
                                             hbuf, hbuf_bf, i == 0, 0);
    gemm_in_bf16<<<dim3((2*DI)/128, TOK/64), 256, 0, stream>>>(
        hbuf_bf, inw_bf + (size_t)i*2*DI*DM, xmbuf, zgbuf);
    xproj_scan1<<<TOK/CHUNK, 512, 0, stream>>>(
        xmbuf, conv_w + i*DI*KC, conv_b + i*DI,
        xpw_bf + (size_t)i*XDIM*DI,
        dt_w + (size_t)i*DI*RDT, dt_b + i*DI, A_log + (size_t)i*DI*NST,
        Dp + i*DI, xdblbuf, hlocbuf, dsumbuf, ylbuf, csbuf);
    scan_pass2<<<(BB*NST*DI*8)/256, 256, 0, stream>>>(
        hlocbuf, dsumbuf, A_log + (size_t)i*DI*NST, hinitbuf);
    scan_pass3<<<BB*NCH*(DI/256), 256, 0, stream>>>(
        csbuf, ylbuf, zgbuf, xdblbuf, A_log + (size_t)i*DI*NST,
        hinitbuf, ybuf_bf);
    gemm_out_bf16<<<dim3(DM/64, TOK/64), 256, 0, stream>>>(
        ybuf_bf, outw_bf + (size_t)i*DM*DI, hidden);
  }

  add_ln_kernel<<<TOK/4, 256, 0, stream>>>(residual, hidden, ids, emb,
                                           normf_w, normf_b, hbuf, hbuf_bf, 0, 1);
  pool1_kernel<<<BB*128, DM, 0, stream>>>(hbuf, partbuf);
  pool_decode_kernel<<<BB, DM, 0, stream>>>(partbuf, dec_w, dec_b, out);
}